// Round 2
// baseline (32602.850 us; speedup 1.0000x reference)
//
#include <hip/hip_runtime.h>
#include <math.h>

#define BB   4
#define SS   64
#define DD   512
#define HH   8
#define DHH  64
#define DFFF 2048
#define LL   2
#define VV   32128
#define TT   16
#define EPSV 1e-6f
#define NEGB (-1e9f)
#define GBLK 256
#define NTHR 256
#define NCOLB 251            // 251 * 128 = 32128 vocab columns

#define BSDc ((size_t)131072)    // B*S*D
#define DD2c ((size_t)262144)    // D*D

// ---------------- device-scope grid barrier (all 256 blocks co-resident) --
__device__ __forceinline__ void gsync(unsigned* bar, unsigned ph) {
    __threadfence();                 // release own stores; compiler barrier
    __syncthreads();
    if (threadIdx.x == 0) {
        unsigned arrived = __hip_atomic_fetch_add(&bar[0], 1u, __ATOMIC_ACQ_REL,
                                                  __HIP_MEMORY_SCOPE_AGENT);
        if (arrived == GBLK - 1) {
            __hip_atomic_store(&bar[0], 0u, __ATOMIC_RELAXED, __HIP_MEMORY_SCOPE_AGENT);
            __hip_atomic_store(&bar[1], ph, __ATOMIC_RELEASE, __HIP_MEMORY_SCOPE_AGENT);
        } else {
            while (__hip_atomic_load(&bar[1], __ATOMIC_ACQUIRE,
                                     __HIP_MEMORY_SCOPE_AGENT) < ph)
                __builtin_amdgcn_s_sleep(2);
        }
    }
    __syncthreads();
    __threadfence();                 // acquire; invalidate L1 before reading others' data
}

// ---------------- row RMSNorm phase: 256 rows over 256 blocks -------------
__device__ void d_rms_row(const float* __restrict__ x, const float* __restrict__ ln,
                          float* __restrict__ h, float* sm) {
    int row = blockIdx.x, tid = threadIdx.x;
    const float* xr = x + (size_t)row * DD;
    float local = 0.f;
    for (int k = tid; k < DD; k += NTHR) { float v = xr[k]; local += v * v; }
    sm[tid] = local; __syncthreads();
    for (int s = 128; s > 0; s >>= 1) { if (tid < s) sm[tid] += sm[tid + s]; __syncthreads(); }
    float scale = 1.0f / sqrtf(sm[0] / DD + EPSV);
    __syncthreads();
    for (int k = tid; k < DD; k += NTHR) h[(size_t)row * DD + k] = xr[k] * scale * ln[k];
}

// ---------------- 64x64 GEMM tile (M=256 rows assumed via tile idx) -------
__device__ void d_gemm_tile(const float* __restrict__ A, const float* __restrict__ W,
                            float* __restrict__ C, const float* __restrict__ res,
                            int K, int N, int relu, int tile, float* sm) {
    float* As = sm;                 // [16][65]
    float* Ws = sm + 16 * 65;       // [16][64]
    int tid = threadIdx.x;
    int tr = tid >> 4, tc = tid & 15;
    int nb = N >> 6;
    int row0 = (tile / nb) * 64, col0 = (tile % nb) * 64;
    float acc[4][4] = {};
    for (int k0 = 0; k0 < K; k0 += 16) {
        for (int i = tid; i < 64 * 16; i += NTHR) {
            int r = i >> 4, kk = i & 15;
            As[kk * 65 + r] = A[(size_t)(row0 + r) * K + k0 + kk];
        }
        for (int i = tid; i < 16 * 64; i += NTHR) {
            int kk = i >> 6, c = i & 63;
            Ws[kk * 64 + c] = W[(size_t)(k0 + kk) * N + col0 + c];
        }
        __syncthreads();
        #pragma unroll
        for (int kk = 0; kk < 16; kk++) {
            float a[4], b[4];
            #pragma unroll
            for (int j = 0; j < 4; j++) { a[j] = As[kk * 65 + tr * 4 + j]; b[j] = Ws[kk * 64 + tc * 4 + j]; }
            #pragma unroll
            for (int r = 0; r < 4; r++)
                #pragma unroll
                for (int c = 0; c < 4; c++) acc[r][c] += a[r] * b[c];
        }
        __syncthreads();
    }
    #pragma unroll
    for (int r = 0; r < 4; r++)
        #pragma unroll
        for (int c = 0; c < 4; c++) {
            int gr = row0 + tr * 4 + r, gc = col0 + tc * 4 + c;
            float v = acc[r][c];
            if (res) v += res[(size_t)gr * N + gc];
            if (relu) v = fmaxf(v, 0.f);
            C[(size_t)gr * N + gc] = v;
        }
}

// ---------------- encoder attention, job = (b,h) --------------------------
__device__ void d_enc_attn(const float* __restrict__ qkv, const float* __restrict__ mask,
                           float* __restrict__ o, int job, float* sm) {
    int b = job / HH, h = job % HH;
    int tid = threadIdx.x;
    int lane = tid & 63, wave = tid >> 6;
    float* qq = sm;                 // [64][65]
    float* kk = sm + 64 * 65;
    float* vv = sm + 2 * 64 * 65;
    for (int i = tid; i < SS * DHH; i += NTHR) {
        int s = i >> 6, d = i & 63;
        size_t src = (size_t)(b * SS + s) * DD + h * DHH + d;
        qq[s * 65 + d] = qkv[src];
        kk[s * 65 + d] = qkv[BSDc + src];
        vv[s * 65 + d] = qkv[2 * BSDc + src];
    }
    __syncthreads();
    float bias = (1.0f - mask[b * SS + lane]) * NEGB;
    for (int r = 0; r < 16; r++) {
        int s = wave * 16 + r;
        float sc = 0.f;
        for (int i = 0; i < DHH; i++) sc += qq[s * 65 + i] * kk[lane * 65 + i];
        sc = sc * 0.125f + bias;
        float m = sc;
        for (int o2 = 32; o2 > 0; o2 >>= 1) m = fmaxf(m, __shfl_xor(m, o2));
        float e = expf(sc - m);
        float sum = e;
        for (int o2 = 32; o2 > 0; o2 >>= 1) sum += __shfl_xor(sum, o2);
        float p = e / sum;
        float acc = 0.f;
        for (int t2 = 0; t2 < SS; t2++) acc += __shfl(p, t2) * vv[t2 * 65 + lane];
        o[(size_t)(b * SS + s) * DD + h * DHH + lane] = acc;
    }
    __syncthreads();
}

// ---------------- small-M (M=4) GEMV, K split over 4 waves ----------------
__device__ void d_gemv4(const float* __restrict__ A, int K, const float* __restrict__ ln,
                        const float* __restrict__ W, float* __restrict__ O, int ostr,
                        int N, const float* __restrict__ res, int relu, int cb, float* sm) {
    float* hA = sm;                 // 4*K
    float* wred = sm + 4 * K;       // [4][4][64]
    int tid = threadIdx.x, lane = tid & 63, wv = tid >> 6;
    {
        const float* ar = A + (size_t)wv * K;
        if (ln) {
            float loc = 0.f;
            for (int k = lane; k < K; k += 64) { float x = ar[k]; loc += x * x; }
            for (int o2 = 32; o2 > 0; o2 >>= 1) loc += __shfl_xor(loc, o2);
            float sc = 1.0f / sqrtf(loc / K + EPSV);
            for (int k = lane; k < K; k += 64) hA[wv * K + k] = ar[k] * sc * ln[k];
        } else {
            for (int k = lane; k < K; k += 64) hA[wv * K + k] = ar[k];
        }
    }
    __syncthreads();
    int col = (cb << 6) + lane;
    int kpw = K >> 2, k0 = wv * kpw;
    float a0 = 0.f, a1 = 0.f, a2 = 0.f, a3 = 0.f;
    for (int k = k0; k < k0 + kpw; k++) {
        float w = W[(size_t)k * N + col];
        a0 += hA[k] * w; a1 += hA[K + k] * w; a2 += hA[2 * K + k] * w; a3 += hA[3 * K + k] * w;
    }
    wred[(wv * 4 + 0) * 64 + lane] = a0;
    wred[(wv * 4 + 1) * 64 + lane] = a1;
    wred[(wv * 4 + 2) * 64 + lane] = a2;
    wred[(wv * 4 + 3) * 64 + lane] = a3;
    __syncthreads();
    float v = wred[(0 * 4 + wv) * 64 + lane] + wred[(1 * 4 + wv) * 64 + lane]
            + wred[(2 * 4 + wv) * 64 + lane] + wred[(3 * 4 + wv) * 64 + lane];
    if (res) v += res[(size_t)wv * ostr + col];
    if (relu) v = fmaxf(v, 0.f);
    O[(size_t)wv * ostr + col] = v;
    __syncthreads();
}

// ---------------- decoder self-attn, wave-level, job = (b,h) --------------
__device__ void d_dec_self(const float* __restrict__ dq, const float* __restrict__ sK,
                           const float* __restrict__ sV, float* __restrict__ o,
                           int l, int p, int job) {
    int b = job >> 3, h = job & 7;
    int lane = threadIdx.x & 63;
    const float* qv = dq + (size_t)b * DD + h * DHH;
    float sc = -1e30f;
    if (lane <= p) {
        const float* kr = sK + (((size_t)(l * BB + b)) * TT + lane) * DD + h * DHH;
        float s2 = 0.f;
        for (int i = 0; i < DHH; i++) s2 += qv[i] * kr[i];
        sc = s2 * 0.125f;
    }
    float m = sc;
    for (int o2 = 32; o2 > 0; o2 >>= 1) m = fmaxf(m, __shfl_xor(m, o2));
    float e = (lane <= p) ? expf(sc - m) : 0.f;
    float sum = e;
    for (int o2 = 32; o2 > 0; o2 >>= 1) sum += __shfl_xor(sum, o2);
    float pr = e / sum;
    float acc = 0.f;
    for (int j = 0; j <= p; j++) {
        float pj = __shfl(pr, j);
        acc += pj * sV[(((size_t)(l * BB + b)) * TT + j) * DD + h * DHH + lane];
    }
    o[(size_t)b * DD + h * DHH + lane] = acc;
}

// ---------------- decoder cross-attn, wave-level --------------------------
__device__ void d_dec_cross(const float* __restrict__ dq, const float* __restrict__ cK,
                            const float* __restrict__ cV, const float* __restrict__ mask,
                            float* __restrict__ o, int l, int job) {
    int b = job >> 3, h = job & 7;
    int lane = threadIdx.x & 63;
    const float* qv = dq + (size_t)b * DD + h * DHH;
    const float* kr = cK + (((size_t)(l * BB + b)) * SS + lane) * DD + h * DHH;
    float s2 = 0.f;
    for (int i = 0; i < DHH; i++) s2 += qv[i] * kr[i];
    float sc = s2 * 0.125f + (1.0f - mask[b * SS + lane]) * NEGB;
    float m = sc;
    for (int o2 = 32; o2 > 0; o2 >>= 1) m = fmaxf(m, __shfl_xor(m, o2));
    float e = expf(sc - m);
    float sum = e;
    for (int o2 = 32; o2 > 0; o2 >>= 1) sum += __shfl_xor(sum, o2);
    float pr = e / sum;
    float acc = 0.f;
    for (int j = 0; j < SS; j++) {
        float pj = __shfl(pr, j);
        acc += pj * cV[(((size_t)(l * BB + b)) * SS + j) * DD + h * DHH + lane];
    }
    o[(size_t)b * DD + h * DHH + lane] = acc;
}

// ===================== the mega-kernel ====================================
__global__ __launch_bounds__(NTHR, 2) void k_mega(
    const int* __restrict__ ids, const float* __restrict__ mask, const float* __restrict__ emb,
    const float* __restrict__ enc_wq, const float* __restrict__ enc_wk,
    const float* __restrict__ enc_wv, const float* __restrict__ enc_wo,
    const float* __restrict__ enc_ln1, const float* __restrict__ enc_w1,
    const float* __restrict__ enc_w2, const float* __restrict__ enc_ln2,
    const float* __restrict__ enc_lnf,
    const float* __restrict__ dec_sq, const float* __restrict__ dec_sk,
    const float* __restrict__ dec_sv, const float* __restrict__ dec_so,
    const float* __restrict__ dec_ln1,
    const float* __restrict__ dec_cq, const float* __restrict__ dec_ck,
    const float* __restrict__ dec_cv, const float* __restrict__ dec_co,
    const float* __restrict__ dec_ln2,
    const float* __restrict__ dec_w1, const float* __restrict__ dec_w2,
    const float* __restrict__ dec_ln3, const float* __restrict__ dec_lnf,
    const float* __restrict__ Wlm,
    float* __restrict__ out, float* __restrict__ wsb) {

    __shared__ float sm[12480];      // 48.75 KB union across all phases
    unsigned* bar = (unsigned*)wsb;
    float* ws = wsb + 16;

    float* xe      = ws;                       // 131072
    float* qkv     = xe + BSDc;                // 3*BSD
    float* hbuf    = qkv + 3 * BSDc;           // 131072
    float* attb    = hbuf + BSDc;              // 131072
    float* ffbuf   = attb + BSDc;              // B*S*DFF = 524288
    float* cK      = ffbuf + (size_t)BB * SS * DFFF;   // 262144
    float* cV      = cK + LL * BSDc;           // 262144
    float* sK      = cV + LL * BSDc;           // 65536
    float* sV      = sK + (size_t)LL * BB * TT * DD;   // 65536
    float* xd      = sV + (size_t)LL * BB * TT * DD;   // 2048
    float* dq      = xd + BB * DD;             // 2048
    float* datt    = dq + BB * DD;             // 2048
    float* dff     = datt + BB * DD;           // 8192
    float* logits  = dff + BB * DFFF;          // 128512
    float* stm     = logits + (size_t)BB * VV; // 1004
    float* sts     = stm + BB * NCOLB;         // 1004
    int*   argx    = (int*)(sts + BB * NCOLB); // 4
    float* partial = sts + BB * NCOLB + 4;     // 251*2048

    const int blk = blockIdx.x;
    const int tid = threadIdx.x;
    const int lane = tid & 63, wave = tid >> 6;
    unsigned ph = 0;
    #define GS() do { ph++; gsync(bar, ph); } while (0)

    // ---------- E0: embedding gather + decoder-input init ----------
    {
        int id = ids[blk];
        const float* src = emb + (size_t)id * DD;
        float* dst = xe + (size_t)blk * DD;
        for (int k = tid; k < DD; k += NTHR) dst[k] = src[k];
        if (blk < BB) {
            float* xdp = xd + (size_t)blk * DD;
            for (int k = tid; k < DD; k += NTHR) xdp[k] = emb[k];   // emb[PAD=0]
        }
    }
    GS();

    // ---------- encoder layers ----------
    for (int l = 0; l < LL; l++) {
        d_rms_row(xe, enc_ln1 + (size_t)l * DD, hbuf, sm); GS();
        if (blk < 96) {
            int m = blk >> 5, t2 = blk & 31;
            const float* W = (m == 0 ? enc_wq : (m == 1 ? enc_wk : enc_wv)) + (size_t)l * DD2c;
            d_gemm_tile(hbuf, W, qkv + (size_t)m * BSDc, nullptr, 512, 512, 0, t2, sm);
        }
        GS();
        if (blk < 32) d_enc_attn(qkv, mask, attb, blk, sm);
        GS();
        if (blk < 32) d_gemm_tile(attb, enc_wo + (size_t)l * DD2c, xe, xe, 512, 512, 0, blk, sm);
        GS();
        d_rms_row(xe, enc_ln2 + (size_t)l * DD, hbuf, sm); GS();
        if (blk < 128) d_gemm_tile(hbuf, enc_w1 + (size_t)l * DD * DFFF, ffbuf, nullptr, 512, 2048, 1, blk, sm);
        GS();
        if (blk < 32) d_gemm_tile(ffbuf, enc_w2 + (size_t)l * DFFF * DD, xe, xe, 2048, 512, 0, blk, sm);
        GS();
    }
    d_rms_row(xe, enc_lnf, hbuf, sm); GS();
    if (blk < 128) {
        int m = blk >> 5, t2 = blk & 31;
        const float* W = (m < 2) ? (dec_ck + (size_t)m * DD2c) : (dec_cv + (size_t)(m - 2) * DD2c);
        float* O = (m < 2) ? (cK + (size_t)m * BSDc) : (cV + (size_t)(m - 2) * BSDc);
        d_gemm_tile(hbuf, W, O, nullptr, 512, 512, 0, t2, sm);
    }
    GS();

    // ---------- decode loop (incremental, KV-cached) ----------
    for (int t = 0; t < TT; t++) {
        for (int l = 0; l < LL; l++) {
            // D1: self qkv (q->dq, k/v->caches at position t)
            if (blk < 24) {
                int m = blk >> 3, cb = blk & 7;
                const float* W = (m == 0 ? dec_sq : (m == 1 ? dec_sk : dec_sv)) + (size_t)l * DD2c;
                float* O; int ostr;
                if (m == 0) { O = dq; ostr = DD; }
                else if (m == 1) { O = sK + (size_t)(l * BB * TT + t) * DD; ostr = TT * DD; }
                else { O = sV + (size_t)(l * BB * TT + t) * DD; ostr = TT * DD; }
                d_gemv4(xd, 512, dec_ln1 + (size_t)l * DD, W, O, ostr, 512, nullptr, 0, cb, sm);
            }
            GS();
            // D2: self attention
            if (blk < 8) d_dec_self(dq, sK, sV, datt, l, t, blk * 4 + wave);
            GS();
            // D3: so-proj + residual
            if (blk < 8) d_gemv4(datt, 512, nullptr, dec_so + (size_t)l * DD2c, xd, DD, 512, xd, 0, blk, sm);
            GS();
            // D4: cq
            if (blk < 8) d_gemv4(xd, 512, dec_ln2 + (size_t)l * DD, dec_cq + (size_t)l * DD2c, dq, DD, 512, nullptr, 0, blk, sm);
            GS();
            // D5: cross attention
            if (blk < 8) d_dec_cross(dq, cK, cV, mask, datt, l, blk * 4 + wave);
            GS();
            // D6: co-proj + residual
            if (blk < 8) d_gemv4(datt, 512, nullptr, dec_co + (size_t)l * DD2c, xd, DD, 512, xd, 0, blk, sm);
            GS();
            // D7: FFN up + relu
            if (blk < 32) d_gemv4(xd, 512, dec_ln3 + (size_t)l * DD, dec_w1 + (size_t)l * DD * DFFF, dff, DFFF, 2048, nullptr, 1, blk, sm);
            GS();
            // D8: FFN down + residual
            if (blk < 8) d_gemv4(dff, 2048, nullptr, dec_w2 + (size_t)l * DFFF * DD, xd, DD, 512, xd, 0, blk, sm);
            GS();
        }

        // ---------- D9: lm_head + per-chunk softmax stats ----------
        {
            float* hA = sm;            // [4][512]
            float* sred = sm + 2048;   // [4][256]
            float* lgl = sm + 2048 + 1024;  // [4][128]
            if (blk < NCOLB) {
                const float* xr = xd + (size_t)wave * DD;
                float loc = 0.f;
                for (int k = lane; k < DD; k += 64) { float v = xr[k]; loc += v * v; }
                for (int o2 = 32; o2 > 0; o2 >>= 1) loc += __shfl_xor(loc, o2);
                float sc = 1.0f / sqrtf(loc / DD + EPSV);
                for (int k = lane; k < DD; k += 64) hA[wave * DD + k] = xr[k] * sc * dec_lnf[k];
                __syncthreads();
                int c = tid & 127;
                int col = blk * 128 + c;
                int k0 = (tid >> 7) * 256;
                float a0 = 0.f, a1 = 0.f, a2 = 0.f, a3 = 0.f;
                for (int k = k0; k < k0 + 256; k++) {
                    float w = Wlm[(size_t)k * VV + col];
                    a0 += hA[k] * w; a1 += hA[512 + k] * w; a2 += hA[1024 + k] * w; a3 += hA[1536 + k] * w;
                }
                sred[tid] = a0; sred[256 + tid] = a1; sred[512 + tid] = a2; sred[768 + tid] = a3;
                __syncthreads();
                if (tid < 128) {
                    #pragma unroll
                    for (int b = 0; b < 4; b++) {
                        float v = sred[b * 256 + tid] + sred[b * 256 + tid + 128];
                        lgl[b * 128 + tid] = v;
                        logits[(size_t)b * VV + col] = v;
                    }
                }
                __syncthreads();
                {
                    int b = wave;
                    float v0 = lgl[b * 128 + lane], v1 = lgl[b * 128 + lane + 64];
                    float mx = fmaxf(v0, v1);
                    for (int o2 = 32; o2 > 0; o2 >>= 1) mx = fmaxf(mx, __shfl_xor(mx, o2));
                    float s = expf(v0 - mx) + expf(v1 - mx);
                    for (int o2 = 32; o2 > 0; o2 >>= 1) s += __shfl_xor(s, o2);
                    if (lane == 0) { stm[b * NCOLB + blk] = mx; sts[b * NCOLB + blk] = s; }
                }
            } else if (blk == NCOLB) {
                if (tid < 4) argx[tid] = 0x7fffffff;
            }
        }
        GS();

        // ---------- D10: global softmax merge, write probs, argmax ----------
        {
            float M = -1e30f, S = 0.f;
            for (int j = lane; j < NCOLB; j += 64) {
                float mj = stm[wave * NCOLB + j], sj = sts[wave * NCOLB + j];
                if (mj > M) { S = S * expf(M - mj) + sj; M = mj; }
                else        { S += sj * expf(mj - M); }
            }
            for (int o2 = 32; o2 > 0; o2 >>= 1) {
                float Mo = __shfl_xor(M, o2), So = __shfl_xor(S, o2);
                if (Mo > M) { S = S * expf(M - Mo) + So; M = Mo; }
                else        { S += So * expf(Mo - M); }
            }
            if (lane == 0) { sm[wave * 2] = M; sm[wave * 2 + 1] = S; }
            __syncthreads();
            if (blk < NCOLB) {
                for (int i = tid; i < 512; i += NTHR) {
                    int b = i >> 7, c = i & 127;
                    int col = blk * 128 + c;
                    float Mb = sm[b * 2], Sb = sm[b * 2 + 1];
                    float lg = logits[(size_t)b * VV + col];
                    out[((size_t)b * TT + t) * VV + col] = expf(lg - Mb) / Sb;
                    if (lg == Mb) atomicMin(&argx[b], col);
                }
            }
            __syncthreads();
        }
        GS();

        // ---------- D11: probs @ emb split-K partials + pred flags ----------
        {
            if (blk < NCOLB) {
                float* smp = sm;   // [4][128]
                for (int i = tid; i < 512; i += NTHR) {
                    int b = i >> 7, c = i & 127;
                    smp[i] = out[((size_t)b * TT + t) * VV + blk * 128 + c];
                }
                __syncthreads();
                float a00 = 0.f, a01 = 0.f, a10 = 0.f, a11 = 0.f;
                float a20 = 0.f, a21 = 0.f, a30 = 0.f, a31 = 0.f;
                const float* eb = emb + (size_t)blk * 128 * DD;
                for (int j = 0; j < 128; j++) {
                    const float* er = eb + (size_t)j * DD;
                    float e0 = er[tid], e1 = er[tid + 256];
                    float p0 = smp[j], p1 = smp[128 + j], p2 = smp[256 + j], p3 = smp[384 + j];
                    a00 += p0 * e0; a01 += p0 * e1;
                    a10 += p1 * e0; a11 += p1 * e1;
                    a20 += p2 * e0; a21 += p2 * e1;
                    a30 += p3 * e0; a31 += p3 * e1;
                }
                float* pp = partial + (size_t)blk * (4 * DD);
                pp[0 * DD + tid] = a00; pp[0 * DD + tid + 256] = a01;
                pp[1 * DD + tid] = a10; pp[1 * DD + tid + 256] = a11;
                pp[2 * DD + tid] = a20; pp[2 * DD + tid + 256] = a21;
                pp[3 * DD + tid] = a30; pp[3 * DD + tid + 256] = a31;
                __syncthreads();
            } else if (blk == 255) {
                if (tid < 4) out[(size_t)BB * TT * VV + tid * TT + t] = (argx[tid] == 0) ? 1.0f : 0.0f;
            }
        }
        GS();

        // ---------- D12: reduce partials -> xd ----------
        if (blk < 32) {
            int e = blk * 64 + lane;
            float acc = 0.f;
            for (int j = wave; j < NCOLB; j += 4) acc += partial[(size_t)j * 2048 + e];
            sm[wave * 64 + lane] = acc;
            __syncthreads();
            if (wave == 0) xd[e] = sm[lane] + sm[64 + lane] + sm[128 + lane] + sm[192 + lane];
            __syncthreads();
        }
        GS();
    }
    #undef GS
}

extern "C" void kernel_launch(void* const* d_in, const int* in_sizes, int n_in,
                              void* d_out, int out_size, void* d_ws, size_t ws_size,
                              hipStream_t stream) {
    const int*   ids     = (const int*)  d_in[0];
    const float* mask    = (const float*)d_in[1];
    const float* emb     = (const float*)d_in[2];
    const float* enc_wq  = (const float*)d_in[3];
    const float* enc_wk  = (const float*)d_in[4];
    const float* enc_wv  = (const float*)d_in[5];
    const float* enc_wo  = (const float*)d_in[6];
    const float* enc_ln1 = (const float*)d_in[7];
    const float* enc_w1  = (const float*)d_in[8];
    const float* enc_w2  = (const float*)d_in[9];
    const float* enc_ln2 = (const float*)d_in[10];
    const float* enc_lnf = (const float*)d_in[11];
    const float* dec_sq  = (const float*)d_in[12];
    const float* dec_sk  = (const float*)d_in[13];
    const float* dec_sv  = (const float*)d_in[14];
    const float* dec_so  = (const float*)d_in[15];
    const float* dec_ln1 = (const float*)d_in[16];
    const float* dec_cq  = (const float*)d_in[17];
    const float* dec_ck  = (const float*)d_in[18];
    const float* dec_cv  = (const float*)d_in[19];
    const float* dec_co  = (const float*)d_in[20];
    const float* dec_ln2 = (const float*)d_in[21];
    const float* dec_w1  = (const float*)d_in[22];
    const float* dec_w2  = (const float*)d_in[23];
    const float* dec_ln3 = (const float*)d_in[24];
    const float* dec_lnf = (const float*)d_in[25];
    const float* lm_head = (const float*)d_in[26];

    // zero the grid-barrier slots (ws is poisoned 0xAA before every launch)
    hipMemsetAsync(d_ws, 0, 64, stream);

    k_mega<<<GBLK, NTHR, 0, stream>>>(
        ids, mask, emb,
        enc_wq, enc_wk, enc_wv, enc_wo, enc_ln1, enc_w1, enc_w2, enc_ln2, enc_lnf,
        dec_sq, dec_sk, dec_sv, dec_so, dec_ln1,
        dec_cq, dec_ck, dec_cv, dec_co, dec_ln2,
        dec_w1, dec_w2, dec_ln3, dec_lnf, lm_head,
        (float*)d_out, (float*)d_ws);
}

// Round 3
// 7493.036 us; speedup vs baseline: 4.3511x; 4.3511x over previous
//
#include <hip/hip_runtime.h>
#include <math.h>

#define BB   4
#define SS   64
#define DD   512
#define HH   8
#define DHH  64
#define DFFF 2048
#define LL   2
#define VV   32128
#define TT   16
#define EPSV 1e-6f
#define NEGB (-1e9f)
#define GBLK 256
#define NTHR 256
#define NCOLB 251            // 251 * 128 = 32128 vocab columns

#define BSDc ((size_t)131072)    // B*S*D
#define DD2c ((size_t)262144)    // D*D
#define AGT  __HIP_MEMORY_SCOPE_AGENT

// ---------------- coherence-point (cache-bypass) access helpers -----------
__device__ __forceinline__ float gld(const float* p) {
    return __hip_atomic_load((float*)p, __ATOMIC_RELAXED, AGT);
}
__device__ __forceinline__ void gst(float* p, float v) {
    __hip_atomic_store(p, v, __ATOMIC_RELAXED, AGT);
}
__device__ __forceinline__ int gldi(const int* p) {
    return __hip_atomic_load((int*)p, __ATOMIC_RELAXED, AGT);
}
__device__ __forceinline__ void gsti(int* p, int v) {
    __hip_atomic_store(p, v, __ATOMIC_RELAXED, AGT);
}

// ---------------- 2-level relaxed tree barrier ----------------------------
// bar layout (dwords, 32-dword = 128B line spacing):
//   bar[0]            root counter
//   bar[(1+g)*32]     group-g arrival counter   (g = 0..15)
//   bar[(17+g)*32]    group-g release flag (monotonic phase number)
__device__ __forceinline__ void bar_core(unsigned* bar, unsigned ph) {
    int g = blockIdx.x >> 4;                    // 16 blocks per group
    unsigned* gc = bar + (size_t)(1 + g) * 32;
    unsigned* gf = bar + (size_t)(17 + g) * 32;
    unsigned a = __hip_atomic_fetch_add(gc, 1u, __ATOMIC_RELAXED, AGT);
    if (a == 15u) {                             // last of group
        __hip_atomic_store(gc, 0u, __ATOMIC_RELAXED, AGT);
        __builtin_amdgcn_s_waitcnt(0);          // reset landed before root inc
        unsigned r = __hip_atomic_fetch_add(bar, 1u, __ATOMIC_RELAXED, AGT);
        if (r == 15u) {                         // last group: release all
            __hip_atomic_store(bar, 0u, __ATOMIC_RELAXED, AGT);
            __builtin_amdgcn_s_waitcnt(0);      // root reset landed before flags
            #pragma unroll
            for (int i = 0; i < 16; i++)
                __hip_atomic_store(bar + (size_t)(17 + i) * 32, ph,
                                   __ATOMIC_RELAXED, AGT);
        }
    }
    while (__hip_atomic_load(gf, __ATOMIC_RELAXED, AGT) < ph)
        __builtin_amdgcn_s_sleep(8);
}

// fence-free grid sync (decode): data moves via gld/gst at coherence point
__device__ __forceinline__ void gsync_nf(unsigned* bar, unsigned ph) {
    __builtin_amdgcn_s_waitcnt(0);   // all this wave's stores acked
    __syncthreads();
    if (threadIdx.x == 0) bar_core(bar, ph);
    __syncthreads();
}
// fenced grid sync (encoder): bulk data via normal cached accesses
__device__ __forceinline__ void gsync_f(unsigned* bar, unsigned ph) {
    __builtin_amdgcn_s_waitcnt(0);
    __syncthreads();
    if (threadIdx.x == 0) { __threadfence(); bar_core(bar, ph); __threadfence(); }
    __syncthreads();
}

// ---------------- row RMSNorm phase: 256 rows over 256 blocks (encoder) ---
__device__ void d_rms_row(const float* __restrict__ x, const float* __restrict__ ln,
                          float* __restrict__ h, float* sm) {
    int row = blockIdx.x, tid = threadIdx.x;
    const float* xr = x + (size_t)row * DD;
    float local = 0.f;
    for (int k = tid; k < DD; k += NTHR) { float v = xr[k]; local += v * v; }
    sm[tid] = local; __syncthreads();
    for (int s = 128; s > 0; s >>= 1) { if (tid < s) sm[tid] += sm[tid + s]; __syncthreads(); }
    float scale = 1.0f / sqrtf(sm[0] / DD + EPSV);
    __syncthreads();
    for (int k = tid; k < DD; k += NTHR) h[(size_t)row * DD + k] = xr[k] * scale * ln[k];
}

// ---------------- 64x64 GEMM tile (encoder) -------------------------------
__device__ void d_gemm_tile(const float* __restrict__ A, const float* __restrict__ W,
                            float* __restrict__ C, const float* __restrict__ res,
                            int K, int N, int relu, int tile, float* sm) {
    float* As = sm;                 // [16][65]
    float* Ws = sm + 16 * 65;       // [16][64]
    int tid = threadIdx.x;
    int tr = tid >> 4, tc = tid & 15;
    int nb = N >> 6;
    int row0 = (tile / nb) * 64, col0 = (tile % nb) * 64;
    float acc[4][4] = {};
    for (int k0 = 0; k0 < K; k0 += 16) {
        for (int i = tid; i < 64 * 16; i += NTHR) {
            int r = i >> 4, kk = i & 15;
            As[kk * 65 + r] = A[(size_t)(row0 + r) * K + k0 + kk];
        }
        for (int i = tid; i < 16 * 64; i += NTHR) {
            int kk = i >> 6, c = i & 63;
            Ws[kk * 64 + c] = W[(size_t)(k0 + kk) * N + col0 + c];
        }
        __syncthreads();
        #pragma unroll
        for (int kk = 0; kk < 16; kk++) {
            float a[4], b[4];
            #pragma unroll
            for (int j = 0; j < 4; j++) { a[j] = As[kk * 65 + tr * 4 + j]; b[j] = Ws[kk * 64 + tc * 4 + j]; }
            #pragma unroll
            for (int r = 0; r < 4; r++)
                #pragma unroll
                for (int c = 0; c < 4; c++) acc[r][c] += a[r] * b[c];
        }
        __syncthreads();
    }
    #pragma unroll
    for (int r = 0; r < 4; r++)
        #pragma unroll
        for (int c = 0; c < 4; c++) {
            int gr = row0 + tr * 4 + r, gc = col0 + tc * 4 + c;
            float v = acc[r][c];
            if (res) v += res[(size_t)gr * N + gc];
            if (relu) v = fmaxf(v, 0.f);
            C[(size_t)gr * N + gc] = v;
        }
}

// ---------------- encoder attention, job = (b,h) --------------------------
__device__ void d_enc_attn(const float* __restrict__ qkv, const float* __restrict__ mask,
                           float* __restrict__ o, int job, float* sm) {
    int b = job / HH, h = job % HH;
    int tid = threadIdx.x;
    int lane = tid & 63, wave = tid >> 6;
    float* qq = sm;                 // [64][65]
    float* kk = sm + 64 * 65;
    float* vv = sm + 2 * 64 * 65;
    for (int i = tid; i < SS * DHH; i += NTHR) {
        int s = i >> 6, d = i & 63;
        size_t src = (size_t)(b * SS + s) * DD + h * DHH + d;
        qq[s * 65 + d] = qkv[src];
        kk[s * 65 + d] = qkv[BSDc + src];
        vv[s * 65 + d] = qkv[2 * BSDc + src];
    }
    __syncthreads();
    float bias = (1.0f - mask[b * SS + lane]) * NEGB;
    for (int r = 0; r < 16; r++) {
        int s = wave * 16 + r;
        float sc = 0.f;
        for (int i = 0; i < DHH; i++) sc += qq[s * 65 + i] * kk[lane * 65 + i];
        sc = sc * 0.125f + bias;
        float m = sc;
        for (int o2 = 32; o2 > 0; o2 >>= 1) m = fmaxf(m, __shfl_xor(m, o2));
        float e = expf(sc - m);
        float sum = e;
        for (int o2 = 32; o2 > 0; o2 >>= 1) sum += __shfl_xor(sum, o2);
        float p = e / sum;
        float acc = 0.f;
        for (int t2 = 0; t2 < SS; t2++) acc += __shfl(p, t2) * vv[t2 * 65 + lane];
        o[(size_t)(b * SS + s) * DD + h * DHH + lane] = acc;
    }
    __syncthreads();
}

// ---------------- small-M (M=4) GEMV (decode, coherence-point I/O) --------
__device__ void d_gemv4(const float* __restrict__ A, int K, const float* __restrict__ ln,
                        const float* __restrict__ W, float* __restrict__ O, int ostr,
                        int N, const float* __restrict__ res, int relu, int cb, float* sm) {
    float* hA = sm;                 // 4*K
    float* wred = sm + 4 * K;       // [4][4][64]
    int tid = threadIdx.x, lane = tid & 63, wv = tid >> 6;
    {
        const float* ar = A + (size_t)wv * K;
        if (ln) {
            float loc = 0.f;
            for (int k = lane; k < K; k += 64) { float x = gld(ar + k); loc += x * x; }
            for (int o2 = 32; o2 > 0; o2 >>= 1) loc += __shfl_xor(loc, o2);
            float sc = 1.0f / sqrtf(loc / K + EPSV);
            for (int k = lane; k < K; k += 64) hA[wv * K + k] = gld(ar + k) * sc * ln[k];
        } else {
            for (int k = lane; k < K; k += 64) hA[wv * K + k] = gld(ar + k);
        }
    }
    __syncthreads();
    int col = (cb << 6) + lane;
    int kpw = K >> 2, k0 = wv * kpw;
    float a0 = 0.f, a1 = 0.f, a2 = 0.f, a3 = 0.f;
    for (int k = k0; k < k0 + kpw; k++) {
        float w = W[(size_t)k * N + col];          // weights: normal cached loads
        a0 += hA[k] * w; a1 += hA[K + k] * w; a2 += hA[2 * K + k] * w; a3 += hA[3 * K + k] * w;
    }
    wred[(wv * 4 + 0) * 64 + lane] = a0;
    wred[(wv * 4 + 1) * 64 + lane] = a1;
    wred[(wv * 4 + 2) * 64 + lane] = a2;
    wred[(wv * 4 + 3) * 64 + lane] = a3;
    __syncthreads();
    float v = wred[(0 * 4 + wv) * 64 + lane] + wred[(1 * 4 + wv) * 64 + lane]
            + wred[(2 * 4 + wv) * 64 + lane] + wred[(3 * 4 + wv) * 64 + lane];
    if (res) v += gld(res + (size_t)wv * ostr + col);
    if (relu) v = fmaxf(v, 0.f);
    gst(O + (size_t)wv * ostr + col, v);
    __syncthreads();
}

// ---------------- decoder self-attn, wave-level, job = (b,h) --------------
__device__ void d_dec_self(const float* __restrict__ dq, const float* __restrict__ sK,
                           const float* __restrict__ sV, float* __restrict__ o,
                           int l, int p, int job) {
    int b = job >> 3, h = job & 7;
    int lane = threadIdx.x & 63;
    const float* qv = dq + (size_t)b * DD + h * DHH;
    float sc = -1e30f;
    if (lane <= p) {
        const float* kr = sK + (((size_t)(l * BB + b)) * TT + lane) * DD + h * DHH;
        float s2 = 0.f;
        for (int i = 0; i < DHH; i++) s2 += gld(qv + i) * gld(kr + i);
        sc = s2 * 0.125f;
    }
    float m = sc;
    for (int o2 = 32; o2 > 0; o2 >>= 1) m = fmaxf(m, __shfl_xor(m, o2));
    float e = (lane <= p) ? expf(sc - m) : 0.f;
    float sum = e;
    for (int o2 = 32; o2 > 0; o2 >>= 1) sum += __shfl_xor(sum, o2);
    float pr = e / sum;
    float acc = 0.f;
    for (int j = 0; j <= p; j++) {
        float pj = __shfl(pr, j);
        acc += pj * gld(sV + (((size_t)(l * BB + b)) * TT + j) * DD + h * DHH + lane);
    }
    gst(o + (size_t)b * DD + h * DHH + lane, acc);
}

// ---------------- decoder cross-attn, wave-level --------------------------
// cK/cV are immutable after the encoder's final fenced barrier -> cached loads
__device__ void d_dec_cross(const float* __restrict__ dq, const float* __restrict__ cK,
                            const float* __restrict__ cV, const float* __restrict__ mask,
                            float* __restrict__ o, int l, int job) {
    int b = job >> 3, h = job & 7;
    int lane = threadIdx.x & 63;
    const float* qv = dq + (size_t)b * DD + h * DHH;
    const float* kr = cK + (((size_t)(l * BB + b)) * SS + lane) * DD + h * DHH;
    float s2 = 0.f;
    for (int i = 0; i < DHH; i++) s2 += gld(qv + i) * kr[i];
    float sc = s2 * 0.125f + (1.0f - mask[b * SS + lane]) * NEGB;
    float m = sc;
    for (int o2 = 32; o2 > 0; o2 >>= 1) m = fmaxf(m, __shfl_xor(m, o2));
    float e = expf(sc - m);
    float sum = e;
    for (int o2 = 32; o2 > 0; o2 >>= 1) sum += __shfl_xor(sum, o2);
    float pr = e / sum;
    float acc = 0.f;
    for (int j = 0; j < SS; j++) {
        float pj = __shfl(pr, j);
        acc += pj * cV[(((size_t)(l * BB + b)) * SS + j) * DD + h * DHH + lane];
    }
    gst(o + (size_t)b * DD + h * DHH + lane, acc);
}

// ===================== the mega-kernel ====================================
__global__ __launch_bounds__(NTHR, 2) void k_mega(
    const int* __restrict__ ids, const float* __restrict__ mask, const float* __restrict__ emb,
    const float* __restrict__ enc_wq, const float* __restrict__ enc_wk,
    const float* __restrict__ enc_wv, const float* __restrict__ enc_wo,
    const float* __restrict__ enc_ln1, const float* __restrict__ enc_w1,
    const float* __restrict__ enc_w2, const float* __restrict__ enc_ln2,
    const float* __restrict__ enc_lnf,
    const float* __restrict__ dec_sq, const float* __restrict__ dec_sk,
    const float* __restrict__ dec_sv, const float* __restrict__ dec_so,
    const float* __restrict__ dec_ln1,
    const float* __restrict__ dec_cq, const float* __restrict__ dec_ck,
    const float* __restrict__ dec_cv, const float* __restrict__ dec_co,
    const float* __restrict__ dec_ln2,
    const float* __restrict__ dec_w1, const float* __restrict__ dec_w2,
    const float* __restrict__ dec_ln3, const float* __restrict__ dec_lnf,
    const float* __restrict__ Wlm,
    float* __restrict__ out, float* __restrict__ wsb) {

    __shared__ float sm[12480];      // 48.75 KB union across all phases
    unsigned* bar = (unsigned*)wsb;  // 8 KB barrier region
    float* ws = wsb + 2048;

    float* xe      = ws;                       // 131072
    float* qkv     = xe + BSDc;                // 3*BSD
    float* hbuf    = qkv + 3 * BSDc;           // 131072
    float* attb    = hbuf + BSDc;              // 131072
    float* ffbuf   = attb + BSDc;              // B*S*DFF = 524288
    float* cK      = ffbuf + (size_t)BB * SS * DFFF;   // 262144
    float* cV      = cK + LL * BSDc;           // 262144
    float* sK      = cV + LL * BSDc;           // 65536
    float* sV      = sK + (size_t)LL * BB * TT * DD;   // 65536
    float* xd      = sV + (size_t)LL * BB * TT * DD;   // 2048
    float* dq      = xd + BB * DD;             // 2048
    float* datt    = dq + BB * DD;             // 2048
    float* dff     = datt + BB * DD;           // 8192
    float* logits  = dff + BB * DFFF;          // 128512
    float* stm     = logits + (size_t)BB * VV; // 1004
    float* sts     = stm + BB * NCOLB;         // 1004
    int*   argx    = (int*)(sts + BB * NCOLB); // 4
    float* partial = sts + BB * NCOLB + 4;     // 251*2048

    const int blk = blockIdx.x;
    const int tid = threadIdx.x;
    const int lane = tid & 63, wave = tid >> 6;
    unsigned ph = 0;
    #define GSF() do { ph++; gsync_f(bar, ph); } while (0)
    #define GSN() do { ph++; gsync_nf(bar, ph); } while (0)

    // ---------- E0: embedding gather + decoder-input init ----------
    {
        int id = ids[blk];
        const float* src = emb + (size_t)id * DD;
        float* dst = xe + (size_t)blk * DD;
        for (int k = tid; k < DD; k += NTHR) dst[k] = src[k];
        if (blk < BB) {
            float* xdp = xd + (size_t)blk * DD;
            for (int k = tid; k < DD; k += NTHR) xdp[k] = emb[k];   // emb[PAD=0]
        }
    }
    GSF();

    // ---------- encoder layers (fenced barriers, cached data) ----------
    for (int l = 0; l < LL; l++) {
        d_rms_row(xe, enc_ln1 + (size_t)l * DD, hbuf, sm); GSF();
        if (blk < 96) {
            int m = blk >> 5, t2 = blk & 31;
            const float* W = (m == 0 ? enc_wq : (m == 1 ? enc_wk : enc_wv)) + (size_t)l * DD2c;
            d_gemm_tile(hbuf, W, qkv + (size_t)m * BSDc, nullptr, 512, 512, 0, t2, sm);
        }
        GSF();
        if (blk < 32) d_enc_attn(qkv, mask, attb, blk, sm);
        GSF();
        if (blk < 32) d_gemm_tile(attb, enc_wo + (size_t)l * DD2c, xe, xe, 512, 512, 0, blk, sm);
        GSF();
        d_rms_row(xe, enc_ln2 + (size_t)l * DD, hbuf, sm); GSF();
        if (blk < 128) d_gemm_tile(hbuf, enc_w1 + (size_t)l * DD * DFFF, ffbuf, nullptr, 512, 2048, 1, blk, sm);
        GSF();
        if (blk < 32) d_gemm_tile(ffbuf, enc_w2 + (size_t)l * DFFF * DD, xe, xe, 2048, 512, 0, blk, sm);
        GSF();
    }
    d_rms_row(xe, enc_lnf, hbuf, sm); GSF();
    if (blk < 128) {
        int m = blk >> 5, t2 = blk & 31;
        const float* W = (m < 2) ? (dec_ck + (size_t)m * DD2c) : (dec_cv + (size_t)(m - 2) * DD2c);
        float* O = (m < 2) ? (cK + (size_t)m * BSDc) : (cV + (size_t)(m - 2) * BSDc);
        d_gemm_tile(hbuf, W, O, nullptr, 512, 512, 0, t2, sm);
    }
    GSF();   // publishes cK/cV/xd to coherence point; decode is fence-free

    // ---------- decode loop (incremental, KV-cached) ----------
    for (int t = 0; t < TT; t++) {
        for (int l = 0; l < LL; l++) {
            // D1: self qkv (q->dq, k/v->caches at position t)
            if (blk < 24) {
                int m = blk >> 3, cb = blk & 7;
                const float* W = (m == 0 ? dec_sq : (m == 1 ? dec_sk : dec_sv)) + (size_t)l * DD2c;
                float* O; int ostr;
                if (m == 0) { O = dq; ostr = DD; }
                else if (m == 1) { O = sK + (size_t)(l * BB * TT + t) * DD; ostr = TT * DD; }
                else { O = sV + (size_t)(l * BB * TT + t) * DD; ostr = TT * DD; }
                d_gemv4(xd, 512, dec_ln1 + (size_t)l * DD, W, O, ostr, 512, nullptr, 0, cb, sm);
            }
            GSN();
            // D2: self attention
            if (blk < 8) d_dec_self(dq, sK, sV, datt, l, t, blk * 4 + wave);
            GSN();
            // D3: so-proj + residual
            if (blk < 8) d_gemv4(datt, 512, nullptr, dec_so + (size_t)l * DD2c, xd, DD, 512, xd, 0, blk, sm);
            GSN();
            // D4: cq
            if (blk < 8) d_gemv4(xd, 512, dec_ln2 + (size_t)l * DD, dec_cq + (size_t)l * DD2c, dq, DD, 512, nullptr, 0, blk, sm);
            GSN();
            // D5: cross attention
            if (blk < 8) d_dec_cross(dq, cK, cV, mask, datt, l, blk * 4 + wave);
            GSN();
            // D6: co-proj + residual
            if (blk < 8) d_gemv4(datt, 512, nullptr, dec_co + (size_t)l * DD2c, xd, DD, 512, xd, 0, blk, sm);
            GSN();
            // D7: FFN up + relu
            if (blk < 32) d_gemv4(xd, 512, dec_ln3 + (size_t)l * DD, dec_w1 + (size_t)l * DD * DFFF, dff, DFFF, 2048, nullptr, 1, blk, sm);
            GSN();
            // D8: FFN down + residual
            if (blk < 8) d_gemv4(dff, 2048, nullptr, dec_w2 + (size_t)l * DFFF * DD, xd, DD, 512, xd, 0, blk, sm);
            GSN();
        }

        // ---------- D9: lm_head + per-chunk softmax stats ----------
        {
            float* hA = sm;            // [4][512]
            float* sred = sm + 2048;   // [4][256]
            float* lgl = sm + 2048 + 1024;  // [4][128]
            if (blk < NCOLB) {
                const float* xr = xd + (size_t)wave * DD;
                float loc = 0.f;
                for (int k = lane; k < DD; k += 64) { float v = gld(xr + k); loc += v * v; }
                for (int o2 = 32; o2 > 0; o2 >>= 1) loc += __shfl_xor(loc, o2);
                float sc = 1.0f / sqrtf(loc / DD + EPSV);
                for (int k = lane; k < DD; k += 64) hA[wave * DD + k] = gld(xr + k) * sc * dec_lnf[k];
                __syncthreads();
                int c = tid & 127;
                int col = blk * 128 + c;
                int k0 = (tid >> 7) * 256;
                float a0 = 0.f, a1 = 0.f, a2 = 0.f, a3 = 0.f;
                for (int k = k0; k < k0 + 256; k++) {
                    float w = Wlm[(size_t)k * VV + col];     // cached, stays warm
                    a0 += hA[k] * w; a1 += hA[512 + k] * w; a2 += hA[1024 + k] * w; a3 += hA[1536 + k] * w;
                }
                sred[tid] = a0; sred[256 + tid] = a1; sred[512 + tid] = a2; sred[768 + tid] = a3;
                __syncthreads();
                if (tid < 128) {
                    #pragma unroll
                    for (int b = 0; b < 4; b++) {
                        float v = sred[b * 256 + tid] + sred[b * 256 + tid + 128];
                        lgl[b * 128 + tid] = v;
                        logits[(size_t)b * VV + col] = v;    // re-read by same block only
                    }
                }
                __syncthreads();
                {
                    int b = wave;
                    float v0 = lgl[b * 128 + lane], v1 = lgl[b * 128 + lane + 64];
                    float mx = fmaxf(v0, v1);
                    for (int o2 = 32; o2 > 0; o2 >>= 1) mx = fmaxf(mx, __shfl_xor(mx, o2));
                    float s = expf(v0 - mx) + expf(v1 - mx);
                    for (int o2 = 32; o2 > 0; o2 >>= 1) s += __shfl_xor(s, o2);
                    if (lane == 0) { gst(stm + b * NCOLB + blk, mx); gst(sts + b * NCOLB + blk, s); }
                }
            } else if (blk == NCOLB) {
                if (tid < 4) gsti(argx + tid, 0x7fffffff);
            }
        }
        GSN();

        // ---------- D10: global softmax merge, write probs, argmax ----------
        {
            float M = -1e30f, S = 0.f;
            for (int j = lane; j < NCOLB; j += 64) {
                float mj = gld(stm + wave * NCOLB + j), sj = gld(sts + wave * NCOLB + j);
                if (mj > M) { S = S * expf(M - mj) + sj; M = mj; }
                else        { S += sj * expf(mj - M); }
            }
            for (int o2 = 32; o2 > 0; o2 >>= 1) {
                float Mo = __shfl_xor(M, o2), So = __shfl_xor(S, o2);
                if (Mo > M) { S = S * expf(M - Mo) + So; M = Mo; }
                else        { S += So * expf(Mo - M); }
            }
            if (lane == 0) { sm[wave * 2] = M; sm[wave * 2 + 1] = S; }
            __syncthreads();
            if (blk < NCOLB) {
                for (int i = tid; i < 512; i += NTHR) {
                    int b = i >> 7, c = i & 127;
                    int col = blk * 128 + c;
                    float Mb = sm[b * 2], Sb = sm[b * 2 + 1];
                    float lg = logits[(size_t)b * VV + col];
                    out[((size_t)b * TT + t) * VV + col] = expf(lg - Mb) / Sb;
                    if (lg == Mb) atomicMin(&argx[b], col);
                }
            }
            __syncthreads();
        }
        GSN();

        // ---------- D11: probs @ emb split-K partials + pred flags ----------
        {
            if (blk < NCOLB) {
                float* smp = sm;   // [4][128]
                for (int i = tid; i < 512; i += NTHR) {
                    int b = i >> 7, c = i & 127;
                    smp[i] = out[((size_t)b * TT + t) * VV + blk * 128 + c];  // own block's data
                }
                __syncthreads();
                float a00 = 0.f, a01 = 0.f, a10 = 0.f, a11 = 0.f;
                float a20 = 0.f, a21 = 0.f, a30 = 0.f, a31 = 0.f;
                const float* eb = emb + (size_t)blk * 128 * DD;
                for (int j = 0; j < 128; j++) {
                    const float* er = eb + (size_t)j * DD;
                    float e0 = er[tid], e1 = er[tid + 256];
                    float p0 = smp[j], p1 = smp[128 + j], p2 = smp[256 + j], p3 = smp[384 + j];
                    a00 += p0 * e0; a01 += p0 * e1;
                    a10 += p1 * e0; a11 += p1 * e1;
                    a20 += p2 * e0; a21 += p2 * e1;
                    a30 += p3 * e0; a31 += p3 * e1;
                }
                float* pp = partial + (size_t)blk * (4 * DD);
                gst(pp + 0 * DD + tid, a00); gst(pp + 0 * DD + tid + 256, a01);
                gst(pp + 1 * DD + tid, a10); gst(pp + 1 * DD + tid + 256, a11);
                gst(pp + 2 * DD + tid, a20); gst(pp + 2 * DD + tid + 256, a21);
                gst(pp + 3 * DD + tid, a30); gst(pp + 3 * DD + tid + 256, a31);
                __syncthreads();
            } else if (blk == 255) {
                if (tid < 4) out[(size_t)BB * TT * VV + tid * TT + t] = (gldi(argx + tid) == 0) ? 1.0f : 0.0f;
            }
        }
        GSN();

        // ---------- D12: reduce partials -> xd ----------
        if (blk < 32) {
            int e = blk * 64 + lane;
            float acc = 0.f;
            for (int j = wave; j < NCOLB; j += 4) acc += gld(partial + (size_t)j * 2048 + e);
            sm[wave * 64 + lane] = acc;
            __syncthreads();
            if (wave == 0) gst(xd + e, sm[lane] + sm[64 + lane] + sm[128 + lane] + sm[192 + lane]);
            __syncthreads();
        }
        GSN();
    }
    #undef GSF
    #undef GSN
}

extern "C" void kernel_launch(void* const* d_in, const int* in_sizes, int n_in,
                              void* d_out, int out_size, void* d_ws, size_t ws_size,
                              hipStream_t stream) {
    const int*   ids     = (const int*)  d_in[0];
    const float* mask    = (const float*)d_in[1];
    const float* emb     = (const float*)d_in[2];
    const float* enc_wq  = (const float*)d_in[3];
    const float* enc_wk  = (const float*)d_in[4];
    const float* enc_wv  = (const float*)d_in[5];
    const float* enc_wo  = (const float*)d_in[6];
    const float* enc_ln1 = (const float*)d_in[7];
    const float* enc_w1  = (const float*)d_in[8];
    const float* enc_w2  = (const float*)d_in[9];
    const float* enc_ln2 = (const float*)d_in[10];
    const float* enc_lnf = (const float*)d_in[11];
    const float* dec_sq  = (const float*)d_in[12];
    const float* dec_sk  = (const float*)d_in[13];
    const float* dec_sv  = (const float*)d_in[14];
    const float* dec_so  = (const float*)d_in[15];
    const float* dec_ln1 = (const float*)d_in[16];
    const float* dec_cq  = (const float*)d_in[17];
    const float* dec_ck  = (const float*)d_in[18];
    const float* dec_cv  = (const float*)d_in[19];
    const float* dec_co  = (const float*)d_in[20];
    const float* dec_ln2 = (const float*)d_in[21];
    const float* dec_w1  = (const float*)d_in[22];
    const float* dec_w2  = (const float*)d_in[23];
    const float* dec_ln3 = (const float*)d_in[24];
    const float* dec_lnf = (const float*)d_in[25];
    const float* lm_head = (const float*)d_in[26];

    // zero the barrier region (ws is poisoned 0xAA before every launch)
    hipMemsetAsync(d_ws, 0, 8192, stream);

    k_mega<<<GBLK, NTHR, 0, stream>>>(
        ids, mask, emb,
        enc_wq, enc_wk, enc_wv, enc_wo, enc_ln1, enc_w1, enc_w2, enc_ln2, enc_lnf,
        dec_sq, dec_sk, dec_sv, dec_so, dec_ln1,
        dec_cq, dec_ck, dec_cv, dec_co, dec_ln2,
        dec_w1, dec_w2, dec_ln3, dec_lnf, lm_head,
        (float*)d_out, (float*)d_ws);
}

// Round 4
// 7284.760 us; speedup vs baseline: 4.4755x; 1.0286x over previous
//
#include <hip/hip_runtime.h>
#include <math.h>

#define BB   4
#define SS   64
#define DD   512
#define HH   8
#define DHH  64
#define DFFF 2048
#define LL   2
#define VV   32128
#define TT   16
#define EPSV 1e-6f
#define NEGB (-1e9f)
#define GBLK 256
#define NTHR 256
#define NCOLB 251            // 251 * 128 = 32128 vocab columns

#define BSDc ((size_t)131072)    // B*S*D
#define DD2c ((size_t)262144)    // D*D
#define AGT  __HIP_MEMORY_SCOPE_AGENT

// ---------------- coherence-point (cache-bypass) access helpers -----------
__device__ __forceinline__ float gld(const float* p) {
    return __hip_atomic_load((float*)p, __ATOMIC_RELAXED, AGT);
}
__device__ __forceinline__ void gst(float* p, float v) {
    __hip_atomic_store(p, v, __ATOMIC_RELAXED, AGT);
}
__device__ __forceinline__ int gldi(const int* p) {
    return __hip_atomic_load((int*)p, __ATOMIC_RELAXED, AGT);
}
__device__ __forceinline__ void gsti(int* p, int v) {
    __hip_atomic_store(p, v, __ATOMIC_RELAXED, AGT);
}

// ---------------- 2-level relaxed tree barrier ----------------------------
__device__ __forceinline__ void bar_core(unsigned* bar, unsigned ph) {
    int g = blockIdx.x >> 4;                    // 16 blocks per group
    unsigned* gc = bar + (size_t)(1 + g) * 32;
    unsigned* gf = bar + (size_t)(17 + g) * 32;
    unsigned a = __hip_atomic_fetch_add(gc, 1u, __ATOMIC_RELAXED, AGT);
    if (a == 15u) {                             // last of group
        __hip_atomic_store(gc, 0u, __ATOMIC_RELAXED, AGT);
        __builtin_amdgcn_s_waitcnt(0);
        unsigned r = __hip_atomic_fetch_add(bar, 1u, __ATOMIC_RELAXED, AGT);
        if (r == 15u) {                         // last group: release all
            __hip_atomic_store(bar, 0u, __ATOMIC_RELAXED, AGT);
            __builtin_amdgcn_s_waitcnt(0);
            #pragma unroll
            for (int i = 0; i < 16; i++)
                __hip_atomic_store(bar + (size_t)(17 + i) * 32, ph,
                                   __ATOMIC_RELAXED, AGT);
        }
    }
    while (__hip_atomic_load(gf, __ATOMIC_RELAXED, AGT) < ph)
        __builtin_amdgcn_s_sleep(8);
}
__device__ __forceinline__ void gsync_nf(unsigned* bar, unsigned ph) {
    __builtin_amdgcn_s_waitcnt(0);
    __syncthreads();
    if (threadIdx.x == 0) bar_core(bar, ph);
    __syncthreads();
}
__device__ __forceinline__ void gsync_f(unsigned* bar, unsigned ph) {
    __builtin_amdgcn_s_waitcnt(0);
    __syncthreads();
    if (threadIdx.x == 0) { __threadfence(); bar_core(bar, ph); __threadfence(); }
    __syncthreads();
}

// ---------------- row RMSNorm phase: 256 rows over 256 blocks (encoder) ---
__device__ void d_rms_row(const float* __restrict__ x, const float* __restrict__ ln,
                          float* __restrict__ h, float* sm) {
    int row = blockIdx.x, tid = threadIdx.x;
    const float* xr = x + (size_t)row * DD;
    float local = 0.f;
    for (int k = tid; k < DD; k += NTHR) { float v = xr[k]; local += v * v; }
    sm[tid] = local; __syncthreads();
    for (int s = 128; s > 0; s >>= 1) { if (tid < s) sm[tid] += sm[tid + s]; __syncthreads(); }
    float scale = 1.0f / sqrtf(sm[0] / DD + EPSV);
    __syncthreads();
    for (int k = tid; k < DD; k += NTHR) h[(size_t)row * DD + k] = xr[k] * scale * ln[k];
}

// ---------------- 64x64 GEMM tile (encoder) -------------------------------
__device__ void d_gemm_tile(const float* __restrict__ A, const float* __restrict__ W,
                            float* __restrict__ C, const float* __restrict__ res,
                            int K, int N, int relu, int tile, float* sm) {
    float* As = sm;                 // [16][65]
    float* Ws = sm + 16 * 65;       // [16][64]
    int tid = threadIdx.x;
    int tr = tid >> 4, tc = tid & 15;
    int nb = N >> 6;
    int row0 = (tile / nb) * 64, col0 = (tile % nb) * 64;
    float acc[4][4] = {};
    for (int k0 = 0; k0 < K; k0 += 16) {
        for (int i = tid; i < 64 * 16; i += NTHR) {
            int r = i >> 4, kk = i & 15;
            As[kk * 65 + r] = A[(size_t)(row0 + r) * K + k0 + kk];
        }
        for (int i = tid; i < 16 * 64; i += NTHR) {
            int kk = i >> 6, c = i & 63;
            Ws[kk * 64 + c] = W[(size_t)(k0 + kk) * N + col0 + c];
        }
        __syncthreads();
        #pragma unroll
        for (int kk = 0; kk < 16; kk++) {
            float a[4], b[4];
            #pragma unroll
            for (int j = 0; j < 4; j++) { a[j] = As[kk * 65 + tr * 4 + j]; b[j] = Ws[kk * 64 + tc * 4 + j]; }
            #pragma unroll
            for (int r = 0; r < 4; r++)
                #pragma unroll
                for (int c = 0; c < 4; c++) acc[r][c] += a[r] * b[c];
        }
        __syncthreads();
    }
    #pragma unroll
    for (int r = 0; r < 4; r++)
        #pragma unroll
        for (int c = 0; c < 4; c++) {
            int gr = row0 + tr * 4 + r, gc = col0 + tc * 4 + c;
            float v = acc[r][c];
            if (res) v += res[(size_t)gr * N + gc];
            if (relu) v = fmaxf(v, 0.f);
            C[(size_t)gr * N + gc] = v;
        }
}

// ---------------- encoder attention, job = (b,h) --------------------------
__device__ void d_enc_attn(const float* __restrict__ qkv, const float* __restrict__ mask,
                           float* __restrict__ o, int job, float* sm) {
    int b = job / HH, h = job % HH;
    int tid = threadIdx.x;
    int lane = tid & 63, wave = tid >> 6;
    float* qq = sm;
    float* kk = sm + 64 * 65;
    float* vv = sm + 2 * 64 * 65;
    for (int i = tid; i < SS * DHH; i += NTHR) {
        int s = i >> 6, d = i & 63;
        size_t src = (size_t)(b * SS + s) * DD + h * DHH + d;
        qq[s * 65 + d] = qkv[src];
        kk[s * 65 + d] = qkv[BSDc + src];
        vv[s * 65 + d] = qkv[2 * BSDc + src];
    }
    __syncthreads();
    float bias = (1.0f - mask[b * SS + lane]) * NEGB;
    for (int r = 0; r < 16; r++) {
        int s = wave * 16 + r;
        float sc = 0.f;
        for (int i = 0; i < DHH; i++) sc += qq[s * 65 + i] * kk[lane * 65 + i];
        sc = sc * 0.125f + bias;
        float m = sc;
        for (int o2 = 32; o2 > 0; o2 >>= 1) m = fmaxf(m, __shfl_xor(m, o2));
        float e = expf(sc - m);
        float sum = e;
        for (int o2 = 32; o2 > 0; o2 >>= 1) sum += __shfl_xor(sum, o2);
        float p = e / sum;
        float acc = 0.f;
        for (int t2 = 0; t2 < SS; t2++) acc += __shfl(p, t2) * vv[t2 * 65 + lane];
        o[(size_t)(b * SS + s) * DD + h * DHH + lane] = acc;
    }
    __syncthreads();
}

// ======== wide small-M GEMV, 64-col slice, k-split 16 ways ================
// O[b, col0..col0+63] = act( (rms? A[b,:]) @ W[:, cols] + res )
__device__ void d_gemvw64(const float* __restrict__ A, int K, const float* __restrict__ ln,
                          const float* __restrict__ W, float* __restrict__ O, int ostr,
                          int N, const float* __restrict__ res, int relu,
                          int cb, int priv, float* sm) {
    const int tid = threadIdx.x, lane = tid & 63, wv = tid >> 6;
    float* hAT = sm;                    // K*4
    float* red = sm + K * 4;            // 4096
    float* scl = sm + K * 4 + 4096;     // 4
    if (ln) {
        const float* ar = A + (size_t)wv * K;
        float loc = 0.f;
        for (int k = lane; k < K; k += 64) { float x = gld(ar + k); loc += x * x; }
        for (int o = 32; o > 0; o >>= 1) loc += __shfl_xor(loc, o);
        if (lane == 0) scl[wv] = 1.0f / sqrtf(loc / K + EPSV);
    }
    __syncthreads();
    float s0 = ln ? scl[0] : 1.f, s1 = ln ? scl[1] : 1.f;
    float s2 = ln ? scl[2] : 1.f, s3 = ln ? scl[3] : 1.f;
    for (int k = tid; k < K; k += NTHR) {
        float lw = ln ? ln[k] : 1.0f;
        float4 h;
        h.x = gld(A + k) * s0 * lw;
        h.y = gld(A + K + k) * s1 * lw;
        h.z = gld(A + 2 * K + k) * s2 * lw;
        h.w = gld(A + 3 * K + k) * s3 * lw;
        *(float4*)(hAT + k * 4) = h;
    }
    __syncthreads();
    const int c4 = tid & 15, ks = tid >> 4, KC = K >> 4;
    const float4* W4 = (const float4*)W;
    const int col0 = cb << 6;
    float acc[4][4] = {};
    const int kb = ks * KC;
    #pragma unroll 16
    for (int kk = 0; kk < KC; kk++) {
        int k = kb + kk;
        float4 w4 = W4[(size_t)k * (N >> 2) + (col0 >> 2) + c4];
        float4 h4 = *(float4*)(hAT + k * 4);
        float hb[4] = {h4.x, h4.y, h4.z, h4.w};
        float wb[4] = {w4.x, w4.y, w4.z, w4.w};
        #pragma unroll
        for (int b = 0; b < 4; b++)
            #pragma unroll
            for (int ci = 0; ci < 4; ci++) acc[b][ci] += hb[b] * wb[ci];
    }
    {
        float* rp = red + ks * 256 + c4 * 4;
        #pragma unroll
        for (int b = 0; b < 4; b++)
            #pragma unroll
            for (int ci = 0; ci < 4; ci++) rp[b * 64 + ci] = acc[b][ci];
    }
    __syncthreads();
    {
        int b = tid >> 6, c = tid & 63;
        float v = 0.f;
        #pragma unroll
        for (int k2 = 0; k2 < 16; k2++) v += red[k2 * 256 + tid];
        if (res) v += gld(res + (size_t)b * ostr + col0 + c);
        if (relu) v = fmaxf(v, 0.f);
        if (priv) O[(size_t)b * ostr + col0 + c] = v;
        else      gst(O + (size_t)b * ostr + col0 + c, v);
    }
    __syncthreads();
}

// ======== wide small-M GEMV, 128-col slice, k-split 8 ways ================
__device__ void d_gemvw128(const float* __restrict__ A, int K, const float* __restrict__ ln,
                           const float* __restrict__ W, float* __restrict__ O, int ostr,
                           int N, const float* __restrict__ res, int relu,
                           int cb, float* sm) {
    const int tid = threadIdx.x, lane = tid & 63, wv = tid >> 6;
    float* hAT = sm;
    float* red = sm + K * 4;
    float* scl = sm + K * 4 + 4096;
    if (ln) {
        const float* ar = A + (size_t)wv * K;
        float loc = 0.f;
        for (int k = lane; k < K; k += 64) { float x = gld(ar + k); loc += x * x; }
        for (int o = 32; o > 0; o >>= 1) loc += __shfl_xor(loc, o);
        if (lane == 0) scl[wv] = 1.0f / sqrtf(loc / K + EPSV);
    }
    __syncthreads();
    float s0 = ln ? scl[0] : 1.f, s1 = ln ? scl[1] : 1.f;
    float s2 = ln ? scl[2] : 1.f, s3 = ln ? scl[3] : 1.f;
    for (int k = tid; k < K; k += NTHR) {
        float lw = ln ? ln[k] : 1.0f;
        float4 h;
        h.x = gld(A + k) * s0 * lw;
        h.y = gld(A + K + k) * s1 * lw;
        h.z = gld(A + 2 * K + k) * s2 * lw;
        h.w = gld(A + 3 * K + k) * s3 * lw;
        *(float4*)(hAT + k * 4) = h;
    }
    __syncthreads();
    const int c4 = tid & 31, ks = tid >> 5, KC = K >> 3;
    const float4* W4 = (const float4*)W;
    const int col0 = cb << 7;
    float acc[4][4] = {};
    const int kb = ks * KC;
    #pragma unroll 16
    for (int kk = 0; kk < KC; kk++) {
        int k = kb + kk;
        float4 w4 = W4[(size_t)k * (N >> 2) + (col0 >> 2) + c4];
        float4 h4 = *(float4*)(hAT + k * 4);
        float hb[4] = {h4.x, h4.y, h4.z, h4.w};
        float wb[4] = {w4.x, w4.y, w4.z, w4.w};
        #pragma unroll
        for (int b = 0; b < 4; b++)
            #pragma unroll
            for (int ci = 0; ci < 4; ci++) acc[b][ci] += hb[b] * wb[ci];
    }
    {
        float* rp = red + ks * 512 + c4 * 4;
        #pragma unroll
        for (int b = 0; b < 4; b++)
            #pragma unroll
            for (int ci = 0; ci < 4; ci++) rp[b * 128 + ci] = acc[b][ci];
    }
    __syncthreads();
    #pragma unroll
    for (int i = 0; i < 2; i++) {
        int o = tid + i * 256;
        int b = o >> 7, c = o & 127;
        float v = 0.f;
        #pragma unroll
        for (int k2 = 0; k2 < 8; k2++) v += red[k2 * 512 + o];
        if (res) v += gld(res + (size_t)b * ostr + col0 + c);
        if (relu) v = fmaxf(v, 0.f);
        gst(O + (size_t)b * ostr + col0 + c, v);
    }
    __syncthreads();
}

// ---------------- decoder self-attn, block 8+h, wave = batch --------------
__device__ void d_self2(const float* __restrict__ dq, const float* __restrict__ sKp,
                        const float* __restrict__ sV, float* __restrict__ datt,
                        int l, int p, int h, float* sm) {
    int tid = threadIdx.x, lane = tid & 63, b = tid >> 6;
    float* qs = sm;                 // [4][64]
    qs[b * 64 + lane] = gld(dq + (size_t)b * DD + h * DHH + lane);
    __syncthreads();
    float sc = -1e30f;
    if (lane <= p) {
        const float* kr = sKp + (((size_t)(l * BB + b)) * TT + lane) * DD + h * DHH;
        float s2 = 0.f;
        #pragma unroll 16
        for (int i = 0; i < DHH; i++) s2 += qs[b * 64 + i] * kr[i];   // private, L1-hot
        sc = s2 * 0.125f;
    }
    float m = sc;
    for (int o2 = 32; o2 > 0; o2 >>= 1) m = fmaxf(m, __shfl_xor(m, o2));
    float e = (lane <= p) ? expf(sc - m) : 0.f;
    float sum = e;
    for (int o2 = 32; o2 > 0; o2 >>= 1) sum += __shfl_xor(sum, o2);
    float pr = e / sum;
    float acc = 0.f;
    for (int j = 0; j <= p; j++) {
        float pj = __shfl(pr, j);
        acc += pj * gld(sV + (((size_t)(l * BB + b)) * TT + j) * DD + h * DHH + lane);
    }
    gst(datt + (size_t)b * DD + h * DHH + lane, acc);
    __syncthreads();
}

// ---------------- decoder cross-attn, block h, wave = batch ---------------
__device__ void d_cross2(const float* __restrict__ dq, const float* __restrict__ cK,
                         const float* __restrict__ cV, const float* __restrict__ mask,
                         float* __restrict__ datt, int l, int h, float* sm) {
    int tid = threadIdx.x, lane = tid & 63, b = tid >> 6;
    float* qs = sm;
    qs[b * 64 + lane] = gld(dq + (size_t)b * DD + h * DHH + lane);
    __syncthreads();
    const float* kr = cK + (((size_t)(l * BB + b)) * SS + lane) * DD + h * DHH;
    float s2 = 0.f;
    #pragma unroll 16
    for (int i = 0; i < DHH; i++) s2 += qs[b * 64 + i] * kr[i];       // cached (immutable)
    float sc = s2 * 0.125f + (1.0f - mask[b * SS + lane]) * NEGB;
    float m = sc;
    for (int o2 = 32; o2 > 0; o2 >>= 1) m = fmaxf(m, __shfl_xor(m, o2));
    float e = expf(sc - m);
    float sum = e;
    for (int o2 = 32; o2 > 0; o2 >>= 1) sum += __shfl_xor(sum, o2);
    float pr = e / sum;
    float acc = 0.f;
    for (int j = 0; j < SS; j++) {
        float pj = __shfl(pr, j);
        acc += pj * cV[(((size_t)(l * BB + b)) * SS + j) * DD + h * DHH + lane];
    }
    gst(datt + (size_t)b * DD + h * DHH + lane, acc);
    __syncthreads();
}

// ===================== the mega-kernel ====================================
__global__ __launch_bounds__(NTHR, 2) void k_mega(
    const int* __restrict__ ids, const float* __restrict__ mask, const float* __restrict__ emb,
    const float* __restrict__ enc_wq, const float* __restrict__ enc_wk,
    const float* __restrict__ enc_wv, const float* __restrict__ enc_wo,
    const float* __restrict__ enc_ln1, const float* __restrict__ enc_w1,
    const float* __restrict__ enc_w2, const float* __restrict__ enc_ln2,
    const float* __restrict__ enc_lnf,
    const float* __restrict__ dec_sq, const float* __restrict__ dec_sk,
    const float* __restrict__ dec_sv, const float* __restrict__ dec_so,
    const float* __restrict__ dec_ln1,
    const float* __restrict__ dec_cq, const float* __restrict__ dec_ck,
    const float* __restrict__ dec_cv, const float* __restrict__ dec_co,
    const float* __restrict__ dec_ln2,
    const float* __restrict__ dec_w1, const float* __restrict__ dec_w2,
    const float* __restrict__ dec_ln3, const float* __restrict__ dec_lnf,
    const float* __restrict__ Wlm,
    float* __restrict__ out, float* __restrict__ wsb) {

    __shared__ float sm[12480];      // 48.75 KB
    unsigned* bar = (unsigned*)wsb;  // 8 KB barrier region
    float* ws = wsb + 2048;

    float* xe      = ws;
    float* qkv     = xe + BSDc;
    float* hbuf    = qkv + 3 * BSDc;
    float* attb    = hbuf + BSDc;
    float* ffbuf   = attb + BSDc;
    float* cK      = ffbuf + (size_t)BB * SS * DFFF;
    float* cV      = cK + LL * BSDc;
    float* sK      = cV + LL * BSDc;
    float* sV      = sK + (size_t)LL * BB * TT * DD;
    float* xd      = sV + (size_t)LL * BB * TT * DD;   // 2048
    float* dq      = xd + 2048;
    float* datt    = dq + 2048;
    float* dff     = datt + 2048;              // 8192
    float* stm     = dff + 8192;               // [4][NCOLB] pad 1024
    float* sts     = stm + 1024;
    int*   stix    = (int*)(sts + 1024);
    float* partial = (float*)(stix + 1024);    // [NCOLB][2048]

    const int blk = blockIdx.x;
    const int tid = threadIdx.x;
    const int lane = tid & 63, wave = tid >> 6;
    unsigned ph = 0;
    #define GSF() do { ph++; gsync_f(bar, ph); } while (0)
    #define GSN() do { ph++; gsync_nf(bar, ph); } while (0)

    // ---------- E0: embedding gather + decoder-input init ----------
    {
        int id = ids[blk];
        const float* src = emb + (size_t)id * DD;
        float* dst = xe + (size_t)blk * DD;
        for (int k = tid; k < DD; k += NTHR) dst[k] = src[k];
        if (blk < BB) {
            float* xdp = xd + (size_t)blk * DD;
            for (int k = tid; k < DD; k += NTHR) xdp[k] = emb[k];   // emb[PAD=0]
        }
    }
    GSF();

    // ---------- encoder layers (fenced barriers, cached data) ----------
    for (int l = 0; l < LL; l++) {
        d_rms_row(xe, enc_ln1 + (size_t)l * DD, hbuf, sm); GSF();
        if (blk < 96) {
            int m = blk >> 5, t2 = blk & 31;
            const float* W = (m == 0 ? enc_wq : (m == 1 ? enc_wk : enc_wv)) + (size_t)l * DD2c;
            d_gemm_tile(hbuf, W, qkv + (size_t)m * BSDc, nullptr, 512, 512, 0, t2, sm);
        }
        GSF();
        if (blk < 32) d_enc_attn(qkv, mask, attb, blk, sm);
        GSF();
        if (blk < 32) d_gemm_tile(attb, enc_wo + (size_t)l * DD2c, xe, xe, 512, 512, 0, blk, sm);
        GSF();
        d_rms_row(xe, enc_ln2 + (size_t)l * DD, hbuf, sm); GSF();
        if (blk < 128) d_gemm_tile(hbuf, enc_w1 + (size_t)l * DD * DFFF, ffbuf, nullptr, 512, 2048, 1, blk, sm);
        GSF();
        if (blk < 32) d_gemm_tile(ffbuf, enc_w2 + (size_t)l * DFFF * DD, xe, xe, 2048, 512, 0, blk, sm);
        GSF();
    }
    d_rms_row(xe, enc_lnf, hbuf, sm); GSF();
    if (blk < 128) {
        int m = blk >> 5, t2 = blk & 31;
        const float* W = (m < 2) ? (dec_ck + (size_t)m * DD2c) : (dec_cv + (size_t)(m - 2) * DD2c);
        float* O = (m < 2) ? (cK + (size_t)m * BSDc) : (cV + (size_t)(m - 2) * BSDc);
        d_gemm_tile(hbuf, W, O, nullptr, 512, 512, 0, t2, sm);
    }
    GSF();   // publishes cK/cV/xd; decode is fence-free

    // ---------- decode loop ----------
    for (int tt = 0; tt < TT; tt++) {
        for (int l = 0; l < LL; l++) {
            // P1: self qkv. q: blocks 0..7 (gst). K: blocks 8..15 (PRIVATE). V: 16..23 (gst).
            if (blk < 24) {
                int m = blk >> 3, cb = blk & 7;
                const float* W = (m == 0 ? dec_sq : (m == 1 ? dec_sk : dec_sv)) + (size_t)l * DD2c;
                float* O; int ostr; int priv = (m == 1);
                if (m == 0)      { O = dq; ostr = DD; }
                else             { O = (m == 1 ? sK : sV) + (size_t)(l * BB * TT + tt) * DD; ostr = TT * DD; }
                d_gemvw64(xd, 512, dec_ln1 + (size_t)l * DD, W, O, ostr, 512, nullptr, 0, cb, priv, sm);
            }
            GSN();
            // P2: self attention on blocks 8..15 (K-cache private to these blocks)
            if (blk >= 8 && blk < 16) d_self2(dq, sK, sV, datt, l, tt, blk - 8, sm);
            GSN();
            // P3: so-proj + residual
            if (blk < 8) d_gemvw64(datt, 512, nullptr, dec_so + (size_t)l * DD2c, xd, DD, 512, xd, 0, blk, 0, sm);
            GSN();
            // P4: cq
            if (blk < 8) d_gemvw64(xd, 512, dec_ln2 + (size_t)l * DD, dec_cq + (size_t)l * DD2c, dq, DD, 512, nullptr, 0, blk, 0, sm);
            GSN();
            // P5: cross attention
            if (blk < 8) d_cross2(dq, cK, cV, mask, datt, l, blk, sm);
            GSN();
            // P6: co-proj + residual
            if (blk < 8) d_gemvw64(datt, 512, nullptr, dec_co + (size_t)l * DD2c, xd, DD, 512, xd, 0, blk, 0, sm);
            GSN();
            // P7: FFN up + relu
            if (blk < 16) d_gemvw128(xd, 512, dec_ln3 + (size_t)l * DD, dec_w1 + (size_t)l * DD * DFFF, dff, DFFF, 2048, nullptr, 1, blk, sm);
            GSN();
            // P8: FFN down + residual
            if (blk < 8) d_gemvw64(dff, 2048, nullptr, dec_w2 + (size_t)l * DFFF * DD, xd, DD, 512, xd, 0, blk, 0, sm);
            GSN();
        }

        // ---------- D9': lm_head + local softmax + emb partials ----------
        {
            float* hAT = sm;          // 2048
            float* red = sm + 2048;   // 4096
            float* pT  = sm + 6144;   // 512
            float* msc = sm + 6700;   // 4
            float* lgl = sm + 11968;  // 512 (persists to D10')
            if (blk < NCOLB) {
                {   // rms scale per b (wave b)
                    const float* ar = xd + (size_t)wave * DD;
                    float loc = 0.f;
                    for (int k = lane; k < DD; k += 64) { float x = gld(ar + k); loc += x * x; }
                    for (int o = 32; o > 0; o >>= 1) loc += __shfl_xor(loc, o);
                    if (lane == 0) msc[wave] = 1.0f / sqrtf(loc / DD + EPSV);
                }
                __syncthreads();
                float s0 = msc[0], s1 = msc[1], s2 = msc[2], s3 = msc[3];
                for (int k = tid; k < DD; k += NTHR) {
                    float lw = dec_lnf[k];
                    float4 h;
                    h.x = gld(xd + k) * s0 * lw;
                    h.y = gld(xd + DD + k) * s1 * lw;
                    h.z = gld(xd + 2 * DD + k) * s2 * lw;
                    h.w = gld(xd + 3 * DD + k) * s3 * lw;
                    *(float4*)(hAT + k * 4) = h;
                }
                __syncthreads();
                {   // lm_head GEMV, 128 cols, float4 loads, 8 k-slices
                    int c4 = tid & 31, ks = tid >> 5;
                    const float4* W4 = (const float4*)Wlm;
                    float acc[4][4] = {};
                    int kb = ks * 64;
                    #pragma unroll 16
                    for (int kk = 0; kk < 64; kk++) {
                        int k = kb + kk;
                        float4 w4 = W4[(size_t)k * (VV >> 2) + blk * 32 + c4];
                        float4 h4 = *(float4*)(hAT + k * 4);
                        float hb[4] = {h4.x, h4.y, h4.z, h4.w};
                        float wb[4] = {w4.x, w4.y, w4.z, w4.w};
                        #pragma unroll
                        for (int b = 0; b < 4; b++)
                            #pragma unroll
                            for (int ci = 0; ci < 4; ci++) acc[b][ci] += hb[b] * wb[ci];
                    }
                    float* rp = red + ks * 512 + c4 * 4;
                    #pragma unroll
                    for (int b = 0; b < 4; b++)
                        #pragma unroll
                        for (int ci = 0; ci < 4; ci++) rp[b * 128 + ci] = acc[b][ci];
                }
                __syncthreads();
                {   // logits into LDS (persist)
                    float v1 = 0.f, v2 = 0.f;
                    #pragma unroll
                    for (int k2 = 0; k2 < 8; k2++) { v1 += red[k2 * 512 + tid]; v2 += red[k2 * 512 + tid + 256]; }
                    lgl[tid] = v1; lgl[tid + 256] = v2;
                }
                __syncthreads();
                {   // local max / argmax / sum per b (wave b)
                    int b = wave;
                    float v0 = lgl[b * 128 + lane], v1 = lgl[b * 128 + 64 + lane];
                    float mx = fmaxf(v0, v1);
                    int   ix = (v1 > v0) ? lane + 64 : lane;
                    for (int o = 32; o > 0; o >>= 1) {
                        float om = __shfl_xor(mx, o); int oi = __shfl_xor(ix, o);
                        if (om > mx || (om == mx && oi < ix)) { mx = om; ix = oi; }
                    }
                    float e0 = expf(v0 - mx), e1 = expf(v1 - mx);
                    float s = e0 + e1;
                    for (int o = 32; o > 0; o >>= 1) s += __shfl_xor(s, o);
                    pT[lane * 4 + b] = e0; pT[(lane + 64) * 4 + b] = e1;
                    if (lane == 0) {
                        gst(stm + b * NCOLB + blk, mx);
                        gst(sts + b * NCOLB + blk, s);
                        gsti(stix + b * NCOLB + blk, blk * 128 + ix);
                    }
                }
                __syncthreads();
                {   // emb stream: partial_j[b][512] = sum_row pT[row][b]*emb[row]
                    int c4 = tid & 127, rs = tid >> 7;
                    const float4* E4 = (const float4*)emb;
                    float4 a0 = {0,0,0,0}, a1 = a0, a2 = a0, a3 = a0;
                    int rb = rs * 64;
                    #pragma unroll 8
                    for (int r = 0; r < 64; r++) {
                        int row = rb + r;
                        float4 e4 = E4[((size_t)(blk * 128 + row)) * 128 + c4];
                        float4 p4 = *(float4*)(pT + row * 4);
                        a0.x += p4.x * e4.x; a0.y += p4.x * e4.y; a0.z += p4.x * e4.z; a0.w += p4.x * e4.w;
                        a1.x += p4.y * e4.x; a1.y += p4.y * e4.y; a1.z += p4.y * e4.z; a1.w += p4.y * e4.w;
                        a2.x += p4.z * e4.x; a2.y += p4.z * e4.y; a2.z += p4.z * e4.z; a2.w += p4.z * e4.w;
                        a3.x += p4.w * e4.x; a3.y += p4.w * e4.y; a3.z += p4.w * e4.z; a3.w += p4.w * e4.w;
                    }
                    float* rp = red + rs * 2048 + c4 * 4;
                    rp[0]        = a0.x; rp[1]        = a0.y; rp[2]        = a0.z; rp[3]        = a0.w;
                    rp[512 + 0]  = a1.x; rp[512 + 1]  = a1.y; rp[512 + 2]  = a1.z; rp[512 + 3]  = a1.w;
                    rp[1024 + 0] = a2.x; rp[1024 + 1] = a2.y; rp[1024 + 2] = a2.z; rp[1024 + 3] = a2.w;
                    rp[1536 + 0] = a3.x; rp[1536 + 1] = a3.y; rp[1536 + 2] = a3.z; rp[1536 + 3] = a3.w;
                    __syncthreads();
                    #pragma unroll
                    for (int i = 0; i < 8; i++) {
                        int o = tid + i * 256;
                        gst(partial + (size_t)blk * 2048 + o, red[o] + red[2048 + o]);
                    }
                }
            }
        }
        GSN();

        // ---------- D10': global merge + probs + flags + xd reduce ----------
        {
            float* lgl = sm + 11968;
            float* mM  = sm + 6700;        // M[4], S[4]
            int*   jS  = (int*)(sm + 6708);
            {   // merge per b (wave b)
                int b = wave;
                float M = -1e30f, S = 0.f; int jb = 0;
                for (int j = lane; j < NCOLB; j += 64) {
                    float mj = gld(stm + b * NCOLB + j), sj = gld(sts + b * NCOLB + j);
                    if (mj > M) { S = S * expf(M - mj) + sj; M = mj; jb = j; }
                    else        { S += sj * expf(mj - M); }
                }
                for (int o = 32; o > 0; o >>= 1) {
                    float Mo = __shfl_xor(M, o), So = __shfl_xor(S, o);
                    int jo = __shfl_xor(jb, o);
                    if (Mo > M || (Mo == M && jo < jb)) { S = S * expf(M - Mo) + So; M = Mo; jb = jo; }
                    else { S += So * expf(Mo - M); }
                }
                if (lane == 0) { mM[b] = M; mM[4 + b] = S; jS[b] = jb; }
            }
            __syncthreads();
            if (blk < NCOLB) {       // probs from persisted LDS logits
                #pragma unroll
                for (int i = 0; i < 2; i++) {
                    int o = tid + i * 256;
                    int b = o >> 7, c = o & 127;
                    out[((size_t)b * TT + tt) * VV + blk * 128 + c] = expf(lgl[o] - mM[b]) / mM[4 + b];
                }
            }
            if (blk == 255 && tid < 4) {   // pred flags
                int col = gldi(stix + tid * NCOLB + jS[tid]);
                out[(size_t)BB * TT * VV + tid * TT + tt] = (col == 0) ? 1.0f : 0.0f;
            }
            if (blk < 128) {         // xd reduce: 16 elems per block, 16 j-slices
                float* red2 = sm + 8192;   // 256
                int ei = tid & 15, js = tid >> 4;
                int e = blk * 16 + ei, b = e >> 9;
                float Mb = mM[b], Sb = mM[4 + b];
                float v = 0.f;
                #pragma unroll
                for (int i = 0; i < 16; i++) {
                    int j = js + i * 16;
                    if (j < NCOLB) {
                        float scv = expf(gld(stm + b * NCOLB + j) - Mb);
                        v += gld(partial + (size_t)j * 2048 + e) * scv;
                    }
                }
                red2[js * 16 + ei] = v;
                __syncthreads();
                if (tid < 16) {
                    float sv = 0.f;
                    #pragma unroll
                    for (int j2 = 0; j2 < 16; j2++) sv += red2[j2 * 16 + tid];
                    gst(xd + blk * 16 + tid, sv / Sb);
                }
                __syncthreads();
            }
        }
        GSN();
    }
    #undef GSF
    #undef GSN
}

extern "C" void kernel_launch(void* const* d_in, const int* in_sizes, int n_in,
                              void* d_out, int out_size, void* d_ws, size_t ws_size,
                              hipStream_t stream) {
    const int*   ids     = (const int*)  d_in[0];
    const float* mask    = (const float*)d_in[1];
    const float* emb     = (const float*)d_in[2];
    const float* enc_wq  = (const float*)d_in[3];
    const float* enc_wk  = (const float*)d_in[4];
    const float* enc_wv  = (const float*)d_in[5];
    const float* enc_wo  = (const float*)d_in[6];
    const float* enc_ln1 = (const float*)d_in[7];
    const float* enc_w1  = (const float*)d_in[8];
    const float* enc_w2  = (const float*)d_in[9];
    const float* enc_ln2 = (const float*)d_in[10];
    const float* enc_lnf = (const float*)d_in[11];
    const float* dec_sq  = (const float*)d_in[12];
    const float* dec_sk  = (const float*)d_in[13];
    const float* dec_sv  = (const float*)d_in[14];
    const float* dec_so  = (const float*)d_in[15];
    const float* dec_ln1 = (const float*)d_in[16];
    const float* dec_cq  = (const float*)d_in[17];
    const float* dec_ck  = (const float*)d_in[18];
    const float* dec_cv  = (const float*)d_in[19];
    const float* dec_co  = (const float*)d_in[20];
    const float* dec_ln2 = (const float*)d_in[21];
    const float* dec_w1  = (const float*)d_in[22];
    const float* dec_w2  = (const float*)d_in[23];
    const float* dec_ln3 = (const float*)d_in[24];
    const float* dec_lnf = (const float*)d_in[25];
    const float* lm_head = (const float*)d_in[26];

    hipMemsetAsync(d_ws, 0, 8192, stream);

    k_mega<<<GBLK, NTHR, 0, stream>>>(
        ids, mask, emb,
        enc_wq, enc_wk, enc_wv, enc_wo, enc_ln1, enc_w1, enc_w2, enc_ln2, enc_lnf,
        dec_sq, dec_sk, dec_sv, dec_so, dec_ln1,
        dec_cq, dec_ck, dec_cv, dec_co, dec_ln2,
        dec_w1, dec_w2, dec_ln3, dec_lnf, lm_head,
        (float*)d_out, (float*)d_ws);
}

// Round 5
// 5741.401 us; speedup vs baseline: 5.6786x; 1.2688x over previous
//
#include <hip/hip_runtime.h>
#include <math.h>

#define BB   4
#define SS   64
#define DD   512
#define HH   8
#define DHH  64
#define DFFF 2048
#define LL   2
#define VV   32128
#define TT   16
#define EPSV 1e-6f
#define NEGB (-1e9f)
#define GBLK 512
#define NTHR 256
#define NCH  502             // 502 * 64 = 32128 vocab columns
#define STS  512             // stride for per-chunk stat arrays

#define BSDc ((size_t)131072)    // B*S*D
#define DD2c ((size_t)262144)    // D*D
#define AGT  __HIP_MEMORY_SCOPE_AGENT

// ---------------- coherence-point (cache-bypass) access helpers -----------
__device__ __forceinline__ float gld(const float* p) {
    return __hip_atomic_load((float*)p, __ATOMIC_RELAXED, AGT);
}
__device__ __forceinline__ void gst(float* p, float v) {
    __hip_atomic_store(p, v, __ATOMIC_RELAXED, AGT);
}
__device__ __forceinline__ int gldi(const int* p) {
    return __hip_atomic_load((int*)p, __ATOMIC_RELAXED, AGT);
}
__device__ __forceinline__ void gsti(int* p, int v) {
    __hip_atomic_store(p, v, __ATOMIC_RELAXED, AGT);
}

// ---------------- 2-level relaxed tree barrier (512 blocks) ---------------
// bar layout (dwords, 32-dword = 128B line spacing):
//   bar[0]            root counter
//   bar[(1+g)*32]     group-g arrival counter   (g = 0..31, 16 blocks/group)
//   bar[(33+g)*32]    group-g release flag (monotonic phase number)
__device__ __forceinline__ void bar_core(unsigned* bar, unsigned ph) {
    int g = blockIdx.x >> 4;
    unsigned* gc = bar + (size_t)(1 + g) * 32;
    unsigned* gf = bar + (size_t)(33 + g) * 32;
    unsigned a = __hip_atomic_fetch_add(gc, 1u, __ATOMIC_RELAXED, AGT);
    if (a == 15u) {
        __hip_atomic_store(gc, 0u, __ATOMIC_RELAXED, AGT);
        __builtin_amdgcn_s_waitcnt(0);
        unsigned r = __hip_atomic_fetch_add(bar, 1u, __ATOMIC_RELAXED, AGT);
        if (r == 31u) {
            __hip_atomic_store(bar, 0u, __ATOMIC_RELAXED, AGT);
            __builtin_amdgcn_s_waitcnt(0);
            #pragma unroll
            for (int i = 0; i < 32; i++)
                __hip_atomic_store(bar + (size_t)(33 + i) * 32, ph,
                                   __ATOMIC_RELAXED, AGT);
        }
    }
    while (__hip_atomic_load(gf, __ATOMIC_RELAXED, AGT) < ph)
        __builtin_amdgcn_s_sleep(2);
}
__device__ __forceinline__ void gsync_nf(unsigned* bar, unsigned ph) {
    __builtin_amdgcn_s_waitcnt(0);
    __syncthreads();
    if (threadIdx.x == 0) bar_core(bar, ph);
    __syncthreads();
}
__device__ __forceinline__ void gsync_f(unsigned* bar, unsigned ph) {
    __builtin_amdgcn_s_waitcnt(0);
    __syncthreads();
    if (threadIdx.x == 0) { __threadfence(); bar_core(bar, ph); __threadfence(); }
    __syncthreads();
}

// ---------------- row RMSNorm phase (encoder, blocks < 256) ---------------
__device__ void d_rms_row(const float* __restrict__ x, const float* __restrict__ ln,
                          float* __restrict__ h, float* sm) {
    int row = blockIdx.x, tid = threadIdx.x;
    const float* xr = x + (size_t)row * DD;
    float local = 0.f;
    for (int k = tid; k < DD; k += NTHR) { float v = xr[k]; local += v * v; }
    sm[tid] = local; __syncthreads();
    for (int s = 128; s > 0; s >>= 1) { if (tid < s) sm[tid] += sm[tid + s]; __syncthreads(); }
    float scale = 1.0f / sqrtf(sm[0] / DD + EPSV);
    __syncthreads();
    for (int k = tid; k < DD; k += NTHR) h[(size_t)row * DD + k] = xr[k] * scale * ln[k];
}

// ---------------- 64x64 GEMM tile (encoder) -------------------------------
__device__ void d_gemm_tile(const float* __restrict__ A, const float* __restrict__ W,
                            float* __restrict__ C, const float* __restrict__ res,
                            int K, int N, int relu, int tile, float* sm) {
    float* As = sm;                 // [16][65]
    float* Ws = sm + 16 * 65;       // [16][64]
    int tid = threadIdx.x;
    int tr = tid >> 4, tc = tid & 15;
    int nb = N >> 6;
    int row0 = (tile / nb) * 64, col0 = (tile % nb) * 64;
    float acc[4][4] = {};
    for (int k0 = 0; k0 < K; k0 += 16) {
        for (int i = tid; i < 64 * 16; i += NTHR) {
            int r = i >> 4, kk = i & 15;
            As[kk * 65 + r] = A[(size_t)(row0 + r) * K + k0 + kk];
        }
        for (int i = tid; i < 16 * 64; i += NTHR) {
            int kk = i >> 6, c = i & 63;
            Ws[kk * 64 + c] = W[(size_t)(k0 + kk) * N + col0 + c];
        }
        __syncthreads();
        #pragma unroll
        for (int kk = 0; kk < 16; kk++) {
            float a[4], b[4];
            #pragma unroll
            for (int j = 0; j < 4; j++) { a[j] = As[kk * 65 + tr * 4 + j]; b[j] = Ws[kk * 64 + tc * 4 + j]; }
            #pragma unroll
            for (int r = 0; r < 4; r++)
                #pragma unroll
                for (int c = 0; c < 4; c++) acc[r][c] += a[r] * b[c];
        }
        __syncthreads();
    }
    #pragma unroll
    for (int r = 0; r < 4; r++)
        #pragma unroll
        for (int c = 0; c < 4; c++) {
            int gr = row0 + tr * 4 + r, gc = col0 + tc * 4 + c;
            float v = acc[r][c];
            if (res) v += res[(size_t)gr * N + gc];
            if (relu) v = fmaxf(v, 0.f);
            C[(size_t)gr * N + gc] = v;
        }
}

// ---------------- encoder attention, job = (b,h) --------------------------
__device__ void d_enc_attn(const float* __restrict__ qkv, const float* __restrict__ mask,
                           float* __restrict__ o, int job, float* sm) {
    int b = job / HH, h = job % HH;
    int tid = threadIdx.x;
    int lane = tid & 63, wave = tid >> 6;
    float* qq = sm;
    float* kk = sm + 64 * 65;
    float* vv = sm + 2 * 64 * 65;
    for (int i = tid; i < SS * DHH; i += NTHR) {
        int s = i >> 6, d = i & 63;
        size_t src = (size_t)(b * SS + s) * DD + h * DHH + d;
        qq[s * 65 + d] = qkv[src];
        kk[s * 65 + d] = qkv[BSDc + src];
        vv[s * 65 + d] = qkv[2 * BSDc + src];
    }
    __syncthreads();
    float bias = (1.0f - mask[b * SS + lane]) * NEGB;
    for (int r = 0; r < 16; r++) {
        int s = wave * 16 + r;
        float sc = 0.f;
        for (int i = 0; i < DHH; i++) sc += qq[s * 65 + i] * kk[lane * 65 + i];
        sc = sc * 0.125f + bias;
        float m = sc;
        for (int o2 = 32; o2 > 0; o2 >>= 1) m = fmaxf(m, __shfl_xor(m, o2));
        float e = expf(sc - m);
        float sum = e;
        for (int o2 = 32; o2 > 0; o2 >>= 1) sum += __shfl_xor(sum, o2);
        float p = e / sum;
        float acc = 0.f;
        for (int t2 = 0; t2 < SS; t2++) acc += __shfl(p, t2) * vv[t2 * 65 + lane];
        o[(size_t)(b * SS + s) * DD + h * DHH + lane] = acc;
    }
    __syncthreads();
}

// ======== templated small-M GEMV: NC cols/block, K-split over 256 thr =====
template<int K, int NC>
__device__ void gemvw(const float* __restrict__ A, const float* __restrict__ ln,
                      const float* __restrict__ W, float* __restrict__ O, int ostr,
                      int N, const float* __restrict__ res, int relu,
                      int cb, float* sm) {
    constexpr int C4N = NC / 4;            // float4 col-threads
    constexpr int KSN = NTHR / C4N;        // k-slices
    constexpr int KC  = K / KSN;           // k per slice
    const int tid = threadIdx.x, lane = tid & 63, wv = tid >> 6;
    float* hAT = sm;                       // K*4
    float* red = sm + K * 4;               // 4096
    float* scl = sm + K * 4 + 4096;        // 4
    if (ln) {
        const float* ar = A + (size_t)wv * K;
        float loc = 0.f;
        for (int k = lane; k < K; k += 64) { float x = gld(ar + k); loc += x * x; }
        for (int o = 32; o > 0; o >>= 1) loc += __shfl_xor(loc, o);
        if (lane == 0) scl[wv] = 1.0f / sqrtf(loc / K + EPSV);
    }
    __syncthreads();
    float s0 = ln ? scl[0] : 1.f, s1 = ln ? scl[1] : 1.f;
    float s2 = ln ? scl[2] : 1.f, s3 = ln ? scl[3] : 1.f;
    for (int k = tid; k < K; k += NTHR) {
        float lw = ln ? ln[k] : 1.0f;
        float4 h;
        h.x = gld(A + k) * s0 * lw;
        h.y = gld(A + K + k) * s1 * lw;
        h.z = gld(A + 2 * K + k) * s2 * lw;
        h.w = gld(A + 3 * K + k) * s3 * lw;
        *(float4*)(hAT + k * 4) = h;
    }
    __syncthreads();
    const int c4 = tid % C4N, ks = tid / C4N;
    const float4* W4 = (const float4*)W;
    const int col0 = cb * NC;
    float acc[4][4] = {};
    const int kb = ks * KC;
    #pragma unroll
    for (int kk = 0; kk < KC; kk++) {
        int k = kb + kk;
        float4 w4 = W4[(size_t)k * (N >> 2) + (col0 >> 2) + c4];
        float4 h4 = *(float4*)(hAT + k * 4);
        float hb[4] = {h4.x, h4.y, h4.z, h4.w};
        float wb[4] = {w4.x, w4.y, w4.z, w4.w};
        #pragma unroll
        for (int b = 0; b < 4; b++)
            #pragma unroll
            for (int ci = 0; ci < 4; ci++) acc[b][ci] += hb[b] * wb[ci];
    }
    {
        float* rp = red + ks * (NC * 4) + c4 * 4;
        #pragma unroll
        for (int b = 0; b < 4; b++)
            #pragma unroll
            for (int ci = 0; ci < 4; ci++) rp[b * NC + ci] = acc[b][ci];
    }
    __syncthreads();
    for (int o = tid; o < 4 * NC; o += NTHR) {
        int b = o / NC, c = o % NC;
        float v = 0.f;
        #pragma unroll
        for (int k2 = 0; k2 < KSN; k2++) v += red[k2 * (NC * 4) + o];
        if (res) v += gld(res + (size_t)b * ostr + col0 + c);
        if (relu) v = fmaxf(v, 0.f);
        gst(O + (size_t)b * ostr + col0 + c, v);
    }
    __syncthreads();
}

// ---------------- decoder self-attn, block per head, wave = batch ---------
__device__ void d_self2(const float* __restrict__ dq, const float* __restrict__ sK,
                        const float* __restrict__ sV, float* __restrict__ datt,
                        int l, int p, int h, float* sm) {
    int tid = threadIdx.x, lane = tid & 63, b = tid >> 6;
    float* qs = sm;                 // [4][64]
    qs[b * 64 + lane] = gld(dq + (size_t)b * DD + h * DHH + lane);
    __syncthreads();
    float sc = -1e30f;
    if (lane <= p) {
        const float* kr = sK + (((size_t)(l * BB + b)) * TT + lane) * DD + h * DHH;
        float s2 = 0.f;
        #pragma unroll 16
        for (int i = 0; i < DHH; i++) s2 += qs[b * 64 + i] * gld(kr + i);
        sc = s2 * 0.125f;
    }
    float m = sc;
    for (int o2 = 32; o2 > 0; o2 >>= 1) m = fmaxf(m, __shfl_xor(m, o2));
    float e = (lane <= p) ? expf(sc - m) : 0.f;
    float sum = e;
    for (int o2 = 32; o2 > 0; o2 >>= 1) sum += __shfl_xor(sum, o2);
    float pr = e / sum;
    float acc = 0.f;
    for (int j = 0; j <= p; j++) {
        float pj = __shfl(pr, j);
        acc += pj * gld(sV + (((size_t)(l * BB + b)) * TT + j) * DD + h * DHH + lane);
    }
    gst(datt + (size_t)b * DD + h * DHH + lane, acc);
    __syncthreads();
}

// ---------------- decoder cross-attn, block per head, wave = batch --------
__device__ void d_cross2(const float* __restrict__ dq, const float* __restrict__ cK,
                         const float* __restrict__ cV, const float* __restrict__ mask,
                         float* __restrict__ datt, int l, int h, float* sm) {
    int tid = threadIdx.x, lane = tid & 63, b = tid >> 6;
    float* qs = sm;
    qs[b * 64 + lane] = gld(dq + (size_t)b * DD + h * DHH + lane);
    __syncthreads();
    const float* kr = cK + (((size_t)(l * BB + b)) * SS + lane) * DD + h * DHH;
    float s2 = 0.f;
    #pragma unroll 16
    for (int i = 0; i < DHH; i++) s2 += qs[b * 64 + i] * kr[i];       // immutable: cached
    float sc = s2 * 0.125f + (1.0f - mask[b * SS + lane]) * NEGB;
    float m = sc;
    for (int o2 = 32; o2 > 0; o2 >>= 1) m = fmaxf(m, __shfl_xor(m, o2));
    float e = expf(sc - m);
    float sum = e;
    for (int o2 = 32; o2 > 0; o2 >>= 1) sum += __shfl_xor(sum, o2);
    float pr = e / sum;
    float acc = 0.f;
    for (int j = 0; j < SS; j++) {
        float pj = __shfl(pr, j);
        acc += pj * cV[(((size_t)(l * BB + b)) * SS + j) * DD + h * DHH + lane];
    }
    gst(datt + (size_t)b * DD + h * DHH + lane, acc);
    __syncthreads();
}

// ===================== the mega-kernel ====================================
__global__ __launch_bounds__(NTHR, 2) void k_mega(
    const int* __restrict__ ids, const float* __restrict__ mask, const float* __restrict__ emb,
    const float* __restrict__ enc_wq, const float* __restrict__ enc_wk,
    const float* __restrict__ enc_wv, const float* __restrict__ enc_wo,
    const float* __restrict__ enc_ln1, const float* __restrict__ enc_w1,
    const float* __restrict__ enc_w2, const float* __restrict__ enc_ln2,
    const float* __restrict__ enc_lnf,
    const float* __restrict__ dec_sq, const float* __restrict__ dec_sk,
    const float* __restrict__ dec_sv, const float* __restrict__ dec_so,
    const float* __restrict__ dec_ln1,
    const float* __restrict__ dec_cq, const float* __restrict__ dec_ck,
    const float* __restrict__ dec_cv, const float* __restrict__ dec_co,
    const float* __restrict__ dec_ln2,
    const float* __restrict__ dec_w1, const float* __restrict__ dec_w2,
    const float* __restrict__ dec_ln3, const float* __restrict__ dec_lnf,
    const float* __restrict__ Wlm,
    float* __restrict__ out, float* __restrict__ wsb) {

    __shared__ float sm[12480];      // 48.75 KB
    unsigned* bar = (unsigned*)wsb;  // 16 KB barrier region
    float* ws = wsb + 4096;

    float* xe      = ws;
    float* qkv     = xe + BSDc;
    float* hbuf    = qkv + 3 * BSDc;
    float* attb    = hbuf + BSDc;
    float* ffbuf   = attb + BSDc;
    float* cK      = ffbuf + (size_t)BB * SS * DFFF;
    float* cV      = cK + LL * BSDc;
    float* sK      = cV + LL * BSDc;
    float* sV      = sK + (size_t)LL * BB * TT * DD;
    float* xdA     = sV + (size_t)LL * BB * TT * DD;   // 2048
    float* xdB     = xdA + 2048;
    float* dq      = xdB + 2048;
    float* datt    = dq + 2048;
    float* dff     = datt + 2048;              // 8192
    float* stm     = dff + 8192;               // [4][STS]
    float* sts     = stm + 4 * STS;
    int*   stix    = (int*)(sts + 4 * STS);

    const int blk = blockIdx.x;
    const int tid = threadIdx.x;
    const int lane = tid & 63, wave = tid >> 6;
    unsigned ph = 0;
    #define GSF() do { ph++; gsync_f(bar, ph); } while (0)
    #define GSN() do { ph++; gsync_nf(bar, ph); } while (0)

    // ---------- E0: embedding gather + decoder-input init ----------
    if (blk < 256) {
        int id = ids[blk];
        const float* src = emb + (size_t)id * DD;
        float* dst = xe + (size_t)blk * DD;
        for (int k = tid; k < DD; k += NTHR) dst[k] = src[k];
        if (blk < BB) {
            float* xdp = xdA + (size_t)blk * DD;
            for (int k = tid; k < DD; k += NTHR) xdp[k] = emb[k];   // emb[PAD=0]
        }
    }
    GSF();

    // ---------- encoder layers (fenced barriers, cached data) ----------
    for (int l = 0; l < LL; l++) {
        if (blk < 256) d_rms_row(xe, enc_ln1 + (size_t)l * DD, hbuf, sm);
        GSF();
        if (blk < 96) {
            int m = blk >> 5, t2 = blk & 31;
            const float* W = (m == 0 ? enc_wq : (m == 1 ? enc_wk : enc_wv)) + (size_t)l * DD2c;
            d_gemm_tile(hbuf, W, qkv + (size_t)m * BSDc, nullptr, 512, 512, 0, t2, sm);
        }
        GSF();
        if (blk < 32) d_enc_attn(qkv, mask, attb, blk, sm);
        GSF();
        if (blk < 32) d_gemm_tile(attb, enc_wo + (size_t)l * DD2c, xe, xe, 512, 512, 0, blk, sm);
        GSF();
        if (blk < 256) d_rms_row(xe, enc_ln2 + (size_t)l * DD, hbuf, sm);
        GSF();
        if (blk < 128) d_gemm_tile(hbuf, enc_w1 + (size_t)l * DD * DFFF, ffbuf, nullptr, 512, 2048, 1, blk, sm);
        GSF();
        if (blk < 32) d_gemm_tile(ffbuf, enc_w2 + (size_t)l * DFFF * DD, xe, xe, 2048, 512, 0, blk, sm);
        GSF();
    }
    if (blk < 256) d_rms_row(xe, enc_lnf, hbuf, sm);
    GSF();
    if (blk < 128) {
        int m = blk >> 5, t2 = blk & 31;
        const float* W = (m < 2) ? (dec_ck + (size_t)m * DD2c) : (dec_cv + (size_t)(m - 2) * DD2c);
        float* O = (m < 2) ? (cK + (size_t)m * BSDc) : (cV + (size_t)(m - 2) * BSDc);
        d_gemm_tile(hbuf, W, O, nullptr, 512, 512, 0, t2, sm);
    }
    GSF();   // publishes cK/cV/xdA; decode is fence-free

    // ---------- decode loop ----------
    for (int tt = 0; tt < TT; tt++) {
        float* xc = (tt & 1) ? xdB : xdA;      // current decoder state
        float* xn = (tt & 1) ? xdA : xdB;      // next (accumulated in D10)
        for (int l = 0; l < LL; l++) {
            // P1: self qkv — 96 blocks (3 mats x 32 col-chunks of 16)
            if (blk < 96) {
                int m = blk >> 5, cb = blk & 31;
                const float* W = (m == 0 ? dec_sq : (m == 1 ? dec_sk : dec_sv)) + (size_t)l * DD2c;
                float* O; int ostr;
                if (m == 0) { O = dq; ostr = DD; }
                else { O = (m == 1 ? sK : sV) + (size_t)(l * BB * TT + tt) * DD; ostr = TT * DD; }
                gemvw<512, 16>(xc, dec_ln1 + (size_t)l * DD, W, O, ostr, 512, nullptr, 0, cb, sm);
            }
            GSN();
            // P2: self attention — 8 blocks (one per head)
            if (blk < 8) d_self2(dq, sK, sV, datt, l, tt, blk, sm);
            GSN();
            // P3: so-proj + residual — 32 blocks
            if (blk < 32) gemvw<512, 16>(datt, nullptr, dec_so + (size_t)l * DD2c, xc, DD, 512, xc, 0, blk, sm);
            GSN();
            // P4: cq — 32 blocks
            if (blk < 32) gemvw<512, 16>(xc, dec_ln2 + (size_t)l * DD, dec_cq + (size_t)l * DD2c, dq, DD, 512, nullptr, 0, blk, sm);
            GSN();
            // P5: cross attention — 8 blocks
            if (blk < 8) d_cross2(dq, cK, cV, mask, datt, l, blk, sm);
            GSN();
            // P6: co-proj + residual — 32 blocks
            if (blk < 32) gemvw<512, 16>(datt, nullptr, dec_co + (size_t)l * DD2c, xc, DD, 512, xc, 0, blk, sm);
            GSN();
            // P7: FFN up + relu — 128 blocks
            if (blk < 128) gemvw<512, 16>(xc, dec_ln3 + (size_t)l * DD, dec_w1 + (size_t)l * DD * DFFF, dff, DFFF, 2048, nullptr, 1, blk, sm);
            GSN();
            // P8: FFN down + residual — 64 blocks (K=2048, 8-col chunks)
            if (blk < 64) gemvw<2048, 8>(dff, nullptr, dec_w2 + (size_t)l * DFFF * DD, xc, DD, 512, xc, 0, blk, sm);
            GSN();
        }

        // ---------- D9: lm_head (64 cols/block) + local softmax stats ----------
        {
            float* hAT = sm;            // 2048
            float* red = sm + 2048;     // 4096
            float* msc = sm + 6144;     // 4
            float* lgl = sm + 12224;    // 256 (persists to D10)
            if (blk < NCH) {
                {   // rms scale per b (wave b)
                    const float* ar = xc + (size_t)wave * DD;
                    float loc = 0.f;
                    for (int k = lane; k < DD; k += 64) { float x = gld(ar + k); loc += x * x; }
                    for (int o = 32; o > 0; o >>= 1) loc += __shfl_xor(loc, o);
                    if (lane == 0) msc[wave] = 1.0f / sqrtf(loc / DD + EPSV);
                }
                __syncthreads();
                float s0 = msc[0], s1 = msc[1], s2 = msc[2], s3 = msc[3];
                for (int k = tid; k < DD; k += NTHR) {
                    float lw = dec_lnf[k];
                    float4 h;
                    h.x = gld(xc + k) * s0 * lw;
                    h.y = gld(xc + DD + k) * s1 * lw;
                    h.z = gld(xc + 2 * DD + k) * s2 * lw;
                    h.w = gld(xc + 3 * DD + k) * s3 * lw;
                    *(float4*)(hAT + k * 4) = h;
                }
                __syncthreads();
                {   // lm_head GEMV: 64 cols, 16 c4-threads x 16 k-slices of 32
                    int c4 = tid & 15, ks = tid >> 4;
                    const float4* W4 = (const float4*)Wlm;
                    float acc[4][4] = {};
                    int kb = ks * 32;
                    #pragma unroll
                    for (int kk = 0; kk < 32; kk++) {
                        int k = kb + kk;
                        float4 w4 = W4[(size_t)k * (VV >> 2) + blk * 16 + c4];
                        float4 h4 = *(float4*)(hAT + k * 4);
                        float hb[4] = {h4.x, h4.y, h4.z, h4.w};
                        float wb[4] = {w4.x, w4.y, w4.z, w4.w};
                        #pragma unroll
                        for (int b = 0; b < 4; b++)
                            #pragma unroll
                            for (int ci = 0; ci < 4; ci++) acc[b][ci] += hb[b] * wb[ci];
                    }
                    float* rp = red + ks * 256 + c4 * 4;
                    #pragma unroll
                    for (int b = 0; b < 4; b++)
                        #pragma unroll
                        for (int ci = 0; ci < 4; ci++) rp[b * 64 + ci] = acc[b][ci];
                }
                __syncthreads();
                {   // logits into LDS (persist): lgl[b*64 + c]
                    float v = 0.f;
                    #pragma unroll
                    for (int k2 = 0; k2 < 16; k2++) v += red[k2 * 256 + tid];
                    lgl[tid] = v;
                }
                __syncthreads();
                {   // per-chunk max/argmax/sum, wave b over its 64 cols
                    int b = wave;
                    float v0 = lgl[b * 64 + lane];
                    float mx = v0; int ix = lane;
                    for (int o = 32; o > 0; o >>= 1) {
                        float om = __shfl_xor(mx, o); int oi = __shfl_xor(ix, o);
                        if (om > mx || (om == mx && oi < ix)) { mx = om; ix = oi; }
                    }
                    float s = expf(v0 - mx);
                    for (int o = 32; o > 0; o >>= 1) s += __shfl_xor(s, o);
                    if (lane == 0) {
                        gst(stm + b * STS + blk, mx);
                        gst(sts + b * STS + blk, s);
                        gsti(stix + b * STS + blk, blk * 64 + ix);
                    }
                }
            } else if (blk == 511) {
                // zero next-state accumulator (nobody touches xn this phase)
                for (int k = tid; k < 2048; k += NTHR) gst(xn + k, 0.f);
            }
        }
        GSN();

        // ---------- D10: global merge + probs + emb (atomicAdd -> xn) ----------
        {
            float* mM  = sm + 6144;        // M[4], S[4]
            int*   jS  = (int*)(sm + 6152);
            float* pT  = sm + 6400;        // [64][4]
            float* red = sm + 2048;        // 4096
            float* lgl = sm + 12224;       // persisted logits
            {   // merge per b (wave b), all blocks
                int b = wave;
                float M = -1e30f, S = 0.f; int jb = 0;
                for (int j = lane; j < NCH; j += 64) {
                    float mj = gld(stm + b * STS + j), sj = gld(sts + b * STS + j);
                    if (mj > M) { S = S * expf(M - mj) + sj; M = mj; jb = j; }
                    else        { S += sj * expf(mj - M); }
                }
                for (int o = 32; o > 0; o >>= 1) {
                    float Mo = __shfl_xor(M, o), So = __shfl_xor(S, o);
                    int jo = __shfl_xor(jb, o);
                    if (Mo > M || (Mo == M && jo < jb)) { S = S * expf(M - Mo) + So; M = Mo; jb = jo; }
                    else { S += So * expf(Mo - M); }
                }
                if (lane == 0) { mM[b] = M; mM[4 + b] = S; jS[b] = jb; }
            }
            __syncthreads();
            if (blk < NCH) {
                {   // final probs for this chunk: write out + stash transposed
                    int b = tid >> 6, c = tid & 63;
                    float p = expf(lgl[tid] - mM[b]) / mM[4 + b];
                    out[((size_t)b * TT + tt) * VV + blk * 64 + c] = p;
                    pT[c * 4 + b] = p;
                }
                __syncthreads();
                {   // emb chunk (same 64 vocab rows as this block's logits!)
                    int c4 = tid & 127, rs = tid >> 7;
                    const float4* E4 = (const float4*)emb;
                    float4 a0 = {0,0,0,0}, a1 = a0, a2 = a0, a3 = a0;
                    int rb = rs * 32;
                    #pragma unroll 8
                    for (int r = 0; r < 32; r++) {
                        int row = rb + r;
                        float4 e4 = E4[((size_t)(blk * 64 + row)) * 128 + c4];
                        float4 p4 = *(float4*)(pT + row * 4);
                        a0.x += p4.x * e4.x; a0.y += p4.x * e4.y; a0.z += p4.x * e4.z; a0.w += p4.x * e4.w;
                        a1.x += p4.y * e4.x; a1.y += p4.y * e4.y; a1.z += p4.y * e4.z; a1.w += p4.y * e4.w;
                        a2.x += p4.z * e4.x; a2.y += p4.z * e4.y; a2.z += p4.z * e4.z; a2.w += p4.z * e4.w;
                        a3.x += p4.w * e4.x; a3.y += p4.w * e4.y; a3.z += p4.w * e4.z; a3.w += p4.w * e4.w;
                    }
                    float* rp = red + rs * 2048 + c4 * 4;
                    rp[0]        = a0.x; rp[1]        = a0.y; rp[2]        = a0.z; rp[3]        = a0.w;
                    rp[512 + 0]  = a1.x; rp[512 + 1]  = a1.y; rp[512 + 2]  = a1.z; rp[512 + 3]  = a1.w;
                    rp[1024 + 0] = a2.x; rp[1024 + 1] = a2.y; rp[1024 + 2] = a2.z; rp[1024 + 3] = a2.w;
                    rp[1536 + 0] = a3.x; rp[1536 + 1] = a3.y; rp[1536 + 2] = a3.z; rp[1536 + 3] = a3.w;
                }
                __syncthreads();
                #pragma unroll
                for (int i = 0; i < 8; i++) {
                    int o = tid + i * 256;
                    atomicAdd(xn + o, red[o] + red[2048 + o]);
                }
            }
            if (blk == 511 && tid < 4) {   // pred flags
                int col = gldi(stix + tid * STS + jS[tid]);
                out[(size_t)BB * TT * VV + tid * TT + tt] = (col == 0) ? 1.0f : 0.0f;
            }
            __syncthreads();
        }
        GSN();
    }
    #undef GSF
    #undef GSN
}

extern "C" void kernel_launch(void* const* d_in, const int* in_sizes, int n_in,
                              void* d_out, int out_size, void* d_ws, size_t ws_size,
                              hipStream_t stream) {
    const int*   ids     = (const int*)  d_in[0];
    const float* mask    = (const float*)d_in[1];
    const float* emb     = (const float*)d_in[2];
    const float* enc_wq  = (const float*)d_in[3];
    const float* enc_wk  = (const float*)d_in[4];
    const float* enc_wv  = (const float*)d_in[5];
    const float* enc_wo  = (const float*)d_in[6];
    const float* enc_ln1 = (const float*)d_in[7];
    const float* enc_w1  = (const float*)d_in[8];
    const float* enc_w2  = (const float*)d_in[9];
    const float* enc_ln2 = (const float*)d_in[10];
    const float* enc_lnf = (const float*)d_in[11];
    const float* dec_sq  = (const float*)d_in[12];
    const float* dec_sk  = (const float*)d_in[13];
    const float* dec_sv  = (const float*)d_in[14];
    const float* dec_so  = (const float*)d_in[15];
    const float* dec_ln1 = (const float*)d_in[16];
    const float* dec_cq  = (const float*)d_in[17];
    const float* dec_ck  = (const float*)d_in[18];
    const float* dec_cv  = (const float*)d_in[19];
    const float* dec_co  = (const float*)d_in[20];
    const float* dec_ln2 = (const float*)d_in[21];
    const float* dec_w1  = (const float*)d_in[22];
    const float* dec_w2  = (const float*)d_in[23];
    const float* dec_ln3 = (const float*)d_in[24];
    const float* dec_lnf = (const float*)d_in[25];
    const float* lm_head = (const float*)d_in[26];

    hipMemsetAsync(d_ws, 0, 16384, stream);

    k_mega<<<GBLK, NTHR, 0, stream>>>(
        ids, mask, emb,
        enc_wq, enc_wk, enc_wv, enc_wo, enc_ln1, enc_w1, enc_w2, enc_ln2, enc_lnf,
        dec_sq, dec_sk, dec_sv, dec_so, dec_ln1,
        dec_cq, dec_ck, dec_cv, dec_co, dec_ln2,
        dec_w1, dec_w2, dec_ln3, dec_lnf, lm_head,
        (float*)d_out, (float*)d_ws);
}